// Round 5
// baseline (963.791 us; speedup 1.0000x reference)
//
#include <hip/hip_runtime.h>
#include <cstdint>
#include <cstddef>

// Problem constants (fixed by the reference)
#define NN    4096      // nodes
#define E0C   32768     // raw edges
#define ETC   (E0C+NN)  // edges + self loops = 36864
#define HC1   8         // heads layer1
#define CC    512       // channels per head (both layers)
#define F_IN  128
#define NEG_SLOPE_F 0.2f
#define ELLW  64        // ELL width; max in-degree ~Poisson(9) << 64
#define GRID  512       // persistent blocks: 2/CU on 256 CUs (guaranteed by launch_bounds+LDS)

typedef __bf16 bf16_t;
typedef __bf16 bf16x8 __attribute__((ext_vector_type(8)));
typedef __bf16 bf16x4 __attribute__((ext_vector_type(4)));
typedef __bf16 bf16x2 __attribute__((ext_vector_type(2)));
typedef float  f32x4  __attribute__((ext_vector_type(4)));

// async global->LDS, 16B per lane; LDS dest must be linear (wave-uniform base + lane*16)
__device__ __forceinline__ void gload_lds16(const void* g, void* l) {
    __builtin_amdgcn_global_load_lds(
        (const __attribute__((address_space(1))) void*)g,
        (__attribute__((address_space(3))) void*)l, 16, 0, 0);
}

// ---- grid barrier: dedicated counter per barrier (no reset -> no ABA), full fences ----
// All GRID blocks are co-resident by construction (launch_bounds(256,2), 34.6KB LDS).
__device__ __forceinline__ void gbar(int* cnts, int idx) {
    __syncthreads();          // block's work done; vmcnt drained
    __threadfence();          // agent-scope fence: writes visible device-wide (L2 wb)
    if (threadIdx.x == 0) {
        __hip_atomic_fetch_add(&cnts[idx], 1, __ATOMIC_ACQ_REL, __HIP_MEMORY_SCOPE_AGENT);
        while (__hip_atomic_load(&cnts[idx], __ATOMIC_ACQUIRE, __HIP_MEMORY_SCOPE_AGENT) < GRID)
            __builtin_amdgcn_s_sleep(8);
    }
    __syncthreads();
    __threadfence();          // acquire side for all threads (cache invalidate)
}

// ---------- prep: region-dispatched standalone kernel (verbatim known-good) ----------
__device__ __forceinline__ void tcast_body(const float* __restrict__ W, bf16_t* __restrict__ Wt,
                                           int K, int N, int bx, int by)
{
    __shared__ float t[32][33];
    int bn = bx * 32, bk = by * 32;
    int tx = threadIdx.x & 31, ty = threadIdx.x >> 5;
    #pragma unroll
    for (int i = 0; i < 32; i += 8)
        t[ty + i][tx] = W[(size_t)(bk + ty + i) * N + bn + tx];
    __syncthreads();
    #pragma unroll
    for (int i = 0; i < 32; i += 8)
        Wt[(size_t)(bn + ty + i) * K + bk + tx] = (bf16_t)t[tx][ty + i];
}

__global__ __launch_bounds__(256) void prep_k(const float* __restrict__ x,
    const float* __restrict__ W1, const float* __restrict__ W2,
    const float* __restrict__ fc1w, const float* __restrict__ a_src1,
    const float* __restrict__ a_dst1, const int* __restrict__ ei,
    bf16_t* __restrict__ x_bf, bf16_t* __restrict__ Wt1, bf16_t* __restrict__ Wt2,
    bf16_t* __restrict__ fc1wt, bf16_t* __restrict__ w1sT,
    int* __restrict__ srcELL, int* __restrict__ indeg)
{
    const int b = blockIdx.x;
    if (b < 512) {
        int i = (b * 256 + threadIdx.x) * 4;
        float4 v = *(const float4*)&x[i];
        bf16x4 o;
        o[0] = (bf16_t)v.x; o[1] = (bf16_t)v.y; o[2] = (bf16_t)v.z; o[3] = (bf16_t)v.w;
        *(bf16x4*)&x_bf[i] = o;
    } else if (b < 1024) {
        int bl = b - 512;
        tcast_body(W1, Wt1, F_IN, 4096, bl % 128, bl / 128);
    } else if (b < 3072) {
        int bl = b - 1024;
        tcast_body(W2, Wt2, 4096, 512, bl % 16, bl / 16);
    } else if (b < 5120) {
        int bl = b - 3072;
        tcast_body(fc1w, fc1wt, 4096, 512, bl % 16, bl / 16);
    } else if (b < 5152) {
        int bl = b - 5120;                     // 0..31
        int wave = threadIdx.x >> 6, lane = threadIdx.x & 63;
        int k = bl * 4 + wave;                 // 0..127
        int hd = lane >> 3;
        int co = (lane & 7) * 64;
        const float* wrow = W1 + (size_t)k * (HC1 * CC) + hd * CC + co;
        const float* vs = a_src1 + hd * CC + co;
        const float* vd = a_dst1 + hd * CC + co;
        float s = 0.f, d = 0.f;
        #pragma unroll 4
        for (int t = 0; t < 64; ++t) {
            float w = wrow[t];
            s += w * vs[t];
            d += w * vd[t];
        }
        #pragma unroll
        for (int off = 1; off < 8; off <<= 1) {
            s += __shfl_xor(s, off);
            d += __shfl_xor(d, off);
        }
        if ((lane & 7) == 0) {
            w1sT[hd * F_IN + k]       = (bf16_t)s;
            w1sT[(hd + 8) * F_IN + k] = (bf16_t)d;
        }
    } else {
        int e = (b - 5152) * 256 + threadIdx.x;
        if (e < ETC) {
            int s, d;
            if (e < E0C) { s = ei[e]; d = ei[E0C + e]; }
            else         { s = e - E0C; d = s; }
            int pos = atomicAdd(&indeg[d], 1);
            if (pos < ELLW) srcELL[d * ELLW + pos] = s;
        }
    }
}

// ---------- phase bodies (verbatim from passed rounds) ----------
__device__ __forceinline__ void alpha1_body(int vb, const bf16_t* __restrict__ x_bf,
    const bf16_t* __restrict__ w1sT, float* __restrict__ as1, float* __restrict__ ad1)
{
    const int wave = threadIdx.x >> 6, lane = threadIdx.x & 63;
    const int bm = vb * 64 + wave * 16;
    const int lm = lane & 15, quad = lane >> 4;
    f32x4 acc = {};
    #pragma unroll
    for (int k0 = 0; k0 < F_IN; k0 += 32) {
        bf16x8 af = *(const bf16x8*)&x_bf[(size_t)(bm + lm) * F_IN + k0 + quad * 8];
        bf16x8 bf = *(const bf16x8*)&w1sT[lm * F_IN + k0 + quad * 8];
        acc = __builtin_amdgcn_mfma_f32_16x16x32_bf16(af, bf, acc, 0, 0, 0);
    }
    #pragma unroll
    for (int r = 0; r < 4; ++r) {
        int n = bm + quad * 4 + r;
        if (lm < 8) as1[n * HC1 + lm] = acc[r];
        else        ad1[n * HC1 + (lm - 8)] = acc[r];
    }
}

__device__ __forceinline__ void aggx_body(int vb, const bf16_t* __restrict__ x_bf,
    const float* __restrict__ as1, const float* __restrict__ ad1,
    const int* __restrict__ indeg, const int* __restrict__ srcELL,
    bf16_t* __restrict__ xagg)
{
    const int wave = threadIdx.x >> 6, lane = threadIdx.x & 63;
    const int n = vb * 4 + wave;
    const int c = lane * 2;
    const int deg = min(indeg[n], ELLW);

    int vsrc = 0;
    float vp[HC1] = {};
    if (lane < deg) {
        vsrc = srcELL[n * ELLW + lane];
        #pragma unroll
        for (int hd = 0; hd < HC1; ++hd) {
            float v = as1[vsrc * HC1 + hd] + ad1[n * HC1 + hd];
            v = (v > 0.f) ? v : NEG_SLOPE_F * v;
            vp[hd] = __expf(v);
        }
    }
    #pragma unroll
    for (int hd = 0; hd < HC1; ++hd) {
        float dsum = vp[hd];
        #pragma unroll
        for (int off = 1; off < 64; off <<= 1)
            dsum += __shfl_xor(dsum, off);
        vp[hd] *= 1.f / dsum;
    }

    float acc[HC1][2] = {};
    int ii = 0;
    for (; ii + 2 <= deg; ii += 2) {
        int s0 = __shfl(vsrc, ii), s1 = __shfl(vsrc, ii + 1);
        bf16x2 r0 = *(const bf16x2*)&x_bf[(size_t)s0 * F_IN + c];
        bf16x2 r1 = *(const bf16x2*)&x_bf[(size_t)s1 * F_IN + c];
        float f00 = (float)r0[0], f01 = (float)r0[1];
        float f10 = (float)r1[0], f11 = (float)r1[1];
        #pragma unroll
        for (int hd = 0; hd < HC1; ++hd) {
            float a0 = __shfl(vp[hd], ii);
            float a1 = __shfl(vp[hd], ii + 1);
            acc[hd][0] += a0 * f00 + a1 * f10;
            acc[hd][1] += a0 * f01 + a1 * f11;
        }
    }
    for (; ii < deg; ++ii) {
        int s = __shfl(vsrc, ii);
        bf16x2 rv = *(const bf16x2*)&x_bf[(size_t)s * F_IN + c];
        float r0 = (float)rv[0], r1 = (float)rv[1];
        #pragma unroll
        for (int hd = 0; hd < HC1; ++hd) {
            float al = __shfl(vp[hd], ii);
            acc[hd][0] += al * r0;
            acc[hd][1] += al * r1;
        }
    }
    #pragma unroll
    for (int hd = 0; hd < HC1; ++hd) {
        bf16x2 o;
        o[0] = (bf16_t)acc[hd][0];
        o[1] = (bf16_t)acc[hd][1];
        *(bf16x2*)&xagg[((size_t)n * HC1 + hd) * F_IN + c] = o;
    }
}

__device__ __forceinline__ void gemmh_body(int bxi, int byi, int hd,
    const bf16_t* __restrict__ xagg, const bf16_t* __restrict__ Wt1,
    const float* __restrict__ b1, bf16_t* __restrict__ out1,
    bf16_t (*As)[4096], bf16_t (*Bs)[4096])
{
    const int tid = threadIdx.x;
    const int bm = bxi * 128, bn = byi * 128;

    const int wave = tid >> 6, lane = tid & 63;
    const int wm = wave >> 1, wn = wave & 1;
    const int lm = lane & 15, quad = lane >> 4;

    const int sr = tid >> 2;
    const int kg = tid & 3;
    const int swcol = (kg ^ (sr & 3)) * 8;

    const bf16_t* Aptr = xagg + ((size_t)(bm + sr) * HC1 + hd) * F_IN + swcol;
    const bf16_t* Bptr = Wt1 + (size_t)(hd * CC + bn + sr) * F_IN + swcol;
    const size_t raskip = (size_t)64 * HC1 * F_IN;
    const size_t rbskip = (size_t)64 * F_IN;

    const int fswz = ((quad ^ (lm & 3)) * 8);

    f32x4 acc[4][4] = {};

    gload_lds16(Aptr,          &As[0][tid * 8]);
    gload_lds16(Aptr + raskip, &As[0][2048 + tid * 8]);
    gload_lds16(Bptr,          &Bs[0][tid * 8]);
    gload_lds16(Bptr + rbskip, &Bs[0][2048 + tid * 8]);
    __syncthreads();

    int cur = 0;
    for (int k0 = 0; k0 < F_IN; k0 += 32) {
        if (k0 + 32 < F_IN) {
            const bf16_t* An = Aptr + (k0 + 32);
            const bf16_t* Bn = Bptr + (k0 + 32);
            gload_lds16(An,          &As[cur ^ 1][tid * 8]);
            gload_lds16(An + raskip, &As[cur ^ 1][2048 + tid * 8]);
            gload_lds16(Bn,          &Bs[cur ^ 1][tid * 8]);
            gload_lds16(Bn + rbskip, &Bs[cur ^ 1][2048 + tid * 8]);
        }
        const bf16_t* Ac = As[cur];
        const bf16_t* Bc = Bs[cur];
        bf16x8 af[4], bfr[4];
        #pragma unroll
        for (int i = 0; i < 4; ++i) {
            af[i]  = *(const bf16x8*)&Ac[(wm * 64 + i * 16 + lm) * 32 + fswz];
            bfr[i] = *(const bf16x8*)&Bc[(wn * 64 + i * 16 + lm) * 32 + fswz];
        }
        #pragma unroll
        for (int mt = 0; mt < 4; ++mt)
            #pragma unroll
            for (int nt = 0; nt < 4; ++nt)
                acc[mt][nt] = __builtin_amdgcn_mfma_f32_16x16x32_bf16(bfr[nt], af[mt], acc[mt][nt], 0, 0, 0);
        __syncthreads();
        cur ^= 1;
    }

    #pragma unroll
    for (int mt = 0; mt < 4; ++mt) {
        int gr = bm + wm * 64 + mt * 16 + lm;
        bf16_t* orow = out1 + (size_t)gr * 4096 + hd * CC;
        #pragma unroll
        for (int nt = 0; nt < 4; ++nt) {
            int gc = bn + wn * 64 + nt * 16 + quad * 4;
            f32x4 bv = *(const f32x4*)&b1[hd * CC + gc];
            bf16x4 o;
            #pragma unroll
            for (int r = 0; r < 4; ++r)
                o[r] = (bf16_t)fmaxf(acc[mt][nt][r] + bv[r], 0.f);
            *(bf16x4*)&orow[gc] = o;
        }
    }
}

__device__ __forceinline__ void gemm128s_body(int bxi, int byi, int kz,
    const bf16_t* __restrict__ A, const bf16_t* __restrict__ Bt,
    bf16_t* __restrict__ Cpart, int M, int N, int K, int Kc,
    bf16_t (*As)[4096], bf16_t (*Bs)[4096])
{
    const int tid = threadIdx.x;
    const int bm = bxi * 128, bn = byi * 128;
    const int k_beg = kz * Kc;
    const int k_end = k_beg + Kc;

    const int wave = tid >> 6, lane = tid & 63;
    const int wm = wave >> 1, wn = wave & 1;
    const int lm = lane & 15, quad = lane >> 4;

    const int sr = tid >> 2;
    const int kg = tid & 3;
    const int swcol = (kg ^ (sr & 3)) * 8;

    const bf16_t* Aptr = A + (size_t)(bm + sr) * K + k_beg + swcol;
    const bf16_t* Bptr = Bt + (size_t)(bn + sr) * K + k_beg + swcol;
    const size_t rowskip = (size_t)64 * K;

    const int fswz = ((quad ^ (lm & 3)) * 8);

    f32x4 acc[4][4] = {};

    gload_lds16(Aptr,           &As[0][tid * 8]);
    gload_lds16(Aptr + rowskip, &As[0][2048 + tid * 8]);
    gload_lds16(Bptr,           &Bs[0][tid * 8]);
    gload_lds16(Bptr + rowskip, &Bs[0][2048 + tid * 8]);
    __syncthreads();

    int cur = 0;
    for (int k0 = k_beg; k0 < k_end; k0 += 32) {
        if (k0 + 32 < k_end) {
            const bf16_t* An = Aptr + (k0 + 32 - k_beg);
            const bf16_t* Bn = Bptr + (k0 + 32 - k_beg);
            gload_lds16(An,           &As[cur ^ 1][tid * 8]);
            gload_lds16(An + rowskip, &As[cur ^ 1][2048 + tid * 8]);
            gload_lds16(Bn,           &Bs[cur ^ 1][tid * 8]);
            gload_lds16(Bn + rowskip, &Bs[cur ^ 1][2048 + tid * 8]);
        }
        const bf16_t* Ac = As[cur];
        const bf16_t* Bc = Bs[cur];
        bf16x8 af[4], bfr[4];
        #pragma unroll
        for (int i = 0; i < 4; ++i) {
            af[i]  = *(const bf16x8*)&Ac[(wm * 64 + i * 16 + lm) * 32 + fswz];
            bfr[i] = *(const bf16x8*)&Bc[(wn * 64 + i * 16 + lm) * 32 + fswz];
        }
        #pragma unroll
        for (int mt = 0; mt < 4; ++mt)
            #pragma unroll
            for (int nt = 0; nt < 4; ++nt)
                acc[mt][nt] = __builtin_amdgcn_mfma_f32_16x16x32_bf16(bfr[nt], af[mt], acc[mt][nt], 0, 0, 0);
        __syncthreads();
        cur ^= 1;
    }

    bf16_t* P = Cpart + (size_t)kz * M * N;
    #pragma unroll
    for (int mt = 0; mt < 4; ++mt) {
        int gr = bm + wm * 64 + mt * 16 + lm;
        #pragma unroll
        for (int nt = 0; nt < 4; ++nt) {
            int gc = bn + wn * 64 + nt * 16 + quad * 4;
            bf16x4 o;
            #pragma unroll
            for (int r = 0; r < 4; ++r)
                o[r] = (bf16_t)acc[mt][nt][r];
            *(bf16x4*)&P[(size_t)gr * N + gc] = o;
        }
    }
}

__device__ __forceinline__ void reduce_body(int vb, const bf16_t* __restrict__ P,
    const float* __restrict__ a_s, const float* __restrict__ a_d,
    bf16_t* __restrict__ h2bf, float* __restrict__ as2, float* __restrict__ ad2)
{
    __shared__ float sred[4][2];
    const int t = threadIdx.x;
    const int i = vb * 1024 + t * 4;
    f32x4 s = {};
    #pragma unroll
    for (int z = 0; z < 4; ++z) {
        bf16x4 pv = *(const bf16x4*)&P[(size_t)z * NN * CC + i];
        #pragma unroll
        for (int j = 0; j < 4; ++j) s[j] += (float)pv[j];
    }
    bf16x4 o;
    #pragma unroll
    for (int j = 0; j < 4; ++j) o[j] = (bf16_t)s[j];
    *(bf16x4*)&h2bf[i] = o;

    const int c = (t & 127) * 4;
    f32x4 va = *(const f32x4*)&a_s[c];
    f32x4 vd = *(const f32x4*)&a_d[c];
    float ls = s[0]*va[0] + s[1]*va[1] + s[2]*va[2] + s[3]*va[3];
    float ld = s[0]*vd[0] + s[1]*vd[1] + s[2]*vd[2] + s[3]*vd[3];
    #pragma unroll
    for (int off = 32; off > 0; off >>= 1) {
        ls += __shfl_down(ls, off);
        ld += __shfl_down(ld, off);
    }
    const int wave = t >> 6, lane = t & 63;
    if (lane == 0) { sred[wave][0] = ls; sred[wave][1] = ld; }
    __syncthreads();
    if (t == 0) {
        as2[vb * 2]     = sred[0][0] + sred[1][0];
        ad2[vb * 2]     = sred[0][1] + sred[1][1];
    }
    if (t == 128) {
        as2[vb * 2 + 1] = sred[2][0] + sred[3][0];
        ad2[vb * 2 + 1] = sred[2][1] + sred[3][1];
    }
    __syncthreads();   // sred reuse across vb iterations
}

__device__ __forceinline__ void agg2_body(int vb, const bf16_t* __restrict__ hbuf,
    const float* __restrict__ as, const float* __restrict__ ad,
    const int* __restrict__ indeg, const int* __restrict__ srcELL,
    const float* __restrict__ bias, bf16_t* __restrict__ outb)
{
    const int wave = threadIdx.x >> 6, lane = threadIdx.x & 63;
    const int n = vb * 4 + wave;
    const int c = lane * 8;

    const int deg = min(indeg[n], ELLW);
    const float adn = ad[n];

    int vsrc = 0; float vp = 0.f;
    if (lane < deg) {
        vsrc = srcELL[n * ELLW + lane];
        float v = as[vsrc] + adn;
        v = (v > 0.f) ? v : NEG_SLOPE_F * v;
        vp = __expf(v);
    }
    float denom = vp;
    #pragma unroll
    for (int off = 1; off < 64; off <<= 1)
        denom += __shfl_xor(denom, off);
    vp *= 1.f / denom;

    float acc[8] = {};
    int ii = 0;
    for (; ii + 4 <= deg; ii += 4) {
        int s0 = __shfl(vsrc, ii),     s1 = __shfl(vsrc, ii + 1);
        int s2 = __shfl(vsrc, ii + 2), s3 = __shfl(vsrc, ii + 3);
        float a0 = __shfl(vp, ii),     a1 = __shfl(vp, ii + 1);
        float a2 = __shfl(vp, ii + 2), a3 = __shfl(vp, ii + 3);
        bf16x8 r0 = *(const bf16x8*)&hbuf[(size_t)s0 * CC + c];
        bf16x8 r1 = *(const bf16x8*)&hbuf[(size_t)s1 * CC + c];
        bf16x8 r2 = *(const bf16x8*)&hbuf[(size_t)s2 * CC + c];
        bf16x8 r3 = *(const bf16x8*)&hbuf[(size_t)s3 * CC + c];
        #pragma unroll
        for (int j = 0; j < 8; ++j) {
            acc[j] += a0 * (float)r0[j];
            acc[j] += a1 * (float)r1[j];
            acc[j] += a2 * (float)r2[j];
            acc[j] += a3 * (float)r3[j];
        }
    }
    for (; ii < deg; ++ii) {
        int s = __shfl(vsrc, ii);
        float al = __shfl(vp, ii);
        bf16x8 rv = *(const bf16x8*)&hbuf[(size_t)s * CC + c];
        #pragma unroll
        for (int j = 0; j < 8; ++j)
            acc[j] += al * (float)rv[j];
    }
    size_t ob = (size_t)n * CC;
    bf16x8 o;
    #pragma unroll
    for (int j = 0; j < 8; ++j)
        o[j] = (bf16_t)fmaxf(acc[j] + bias[c + j], 0.f);
    *(bf16x8*)&outb[ob + c] = o;
}

__device__ __forceinline__ void tail_body(int m, const bf16_t* __restrict__ P,
    const float* __restrict__ fc1b, const float* __restrict__ fc2w,
    const float* __restrict__ fc2b, const float* __restrict__ fc3w,
    const float* __restrict__ fc3b, float* __restrict__ out)
{
    __shared__ float sA[512];
    __shared__ float sF2[128];
    const int t = threadIdx.x;
    const int MN = 512 * 512;
    #pragma unroll
    for (int i = 0; i < 2; ++i) {
        int c = t + i * 256;
        float v = 0.f;
        #pragma unroll
        for (int z = 0; z < 16; ++z)
            v += (float)P[(size_t)z * MN + (size_t)m * 512 + c];
        sA[c] = fmaxf(v + fc1b[c], 0.f);
    }
    __syncthreads();
    if (t < 128) {
        float a0 = 0.f, a1 = 0.f, a2 = 0.f, a3 = 0.f;
        #pragma unroll 4
        for (int k = 0; k < 512; k += 4) {
            a0 += sA[k + 0] * fc2w[(k + 0) * 128 + t];
            a1 += sA[k + 1] * fc2w[(k + 1) * 128 + t];
            a2 += sA[k + 2] * fc2w[(k + 2) * 128 + t];
            a3 += sA[k + 3] * fc2w[(k + 3) * 128 + t];
        }
        sF2[t] = fmaxf((a0 + a1) + (a2 + a3) + fc2b[t], 0.f);
    }
    __syncthreads();
    if (t < 10) {
        float o = fc3b[t];
        #pragma unroll 4
        for (int k = 0; k < 128; ++k)
            o += sF2[k] * fc3w[k * 10 + t];
        out[(size_t)m * 10 + t] = o;
    }
}

// ---------- persistent kernel: phases P1..P8, 7 grid barriers, REGULAR launch ----------
__global__ __launch_bounds__(256, 2) void mega2_k(
    const bf16_t* x_bf, const bf16_t* w1sT, float* as1, float* ad1,
    const int* indeg, const int* srcELL, bf16_t* xagg,
    const bf16_t* Wt1, const float* b1, bf16_t* out1bf,
    const bf16_t* Wt2, bf16_t* part,
    const float* a_src2, const float* a_dst2, bf16_t* h2bf, float* as2, float* ad2,
    const float* b2, bf16_t* out2bf,
    const bf16_t* fc1wt, const float* fc1b,
    const float* fc2w, const float* fc2b, const float* fc3w, const float* fc3b,
    float* out, int* barcnt)
{
    __shared__ bf16_t sAs[2][4096];   // shared by all GEMM phases
    __shared__ bf16_t sBs[2][4096];
    const int bid = blockIdx.x;

    // P1: alpha1 (64 vb)
    for (int vb = bid; vb < 64; vb += GRID)
        alpha1_body(vb, x_bf, w1sT, as1, ad1);
    gbar(barcnt, 0);

    // P2: aggx (1024 vb)
    for (int vb = bid; vb < 1024; vb += GRID)
        aggx_body(vb, x_bf, as1, ad1, indeg, srcELL, xagg);
    gbar(barcnt, 1);

    // P3: gemmh (1024 vb): decode (32,4,8)
    for (int vb = bid; vb < 1024; vb += GRID)
        gemmh_body(vb & 31, (vb >> 5) & 3, vb >> 7, xagg, Wt1, b1, out1bf, sAs, sBs);
    gbar(barcnt, 2);

    // P4: layer-2 GEMM (512 vb): decode (32,4,4), M=4096,N=512,K=4096,Kc=1024
    for (int vb = bid; vb < 512; vb += GRID)
        gemm128s_body(vb & 31, (vb >> 5) & 3, vb >> 7,
                      out1bf, Wt2, part, 4096, 512, 4096, 1024, sAs, sBs);
    gbar(barcnt, 3);

    // P5: reduce h2 + alpha2 (2048 vb)
    for (int vb = bid; vb < 2048; vb += GRID)
        reduce_body(vb, part, a_src2, a_dst2, h2bf, as2, ad2);
    gbar(barcnt, 4);

    // P6: aggregate2 (1024 vb)
    for (int vb = bid; vb < 1024; vb += GRID)
        agg2_body(vb, h2bf, as2, ad2, indeg, srcELL, b2, out2bf);
    gbar(barcnt, 5);

    // P7: fc1 GEMM (256 vb): decode (4,4,16), M=512,N=512,K=4096,Kc=256
    for (int vb = bid; vb < 256; vb += GRID)
        gemm128s_body(vb & 3, (vb >> 2) & 3, vb >> 4,
                      out2bf, fc1wt, part, 512, 512, 4096, 256, sAs, sBs);
    gbar(barcnt, 6);

    // P8: tail (512 vb)
    for (int vb = bid; vb < 512; vb += GRID)
        tail_body(vb, part, fc1b, fc2w, fc2b, fc3w, fc3b, out);
}

extern "C" void kernel_launch(void* const* d_in, const int* in_sizes, int n_in,
                              void* d_out, int out_size, void* d_ws, size_t ws_size,
                              hipStream_t stream) {
    const float* x      = (const float*)d_in[0];
    const int*   ei     = (const int*)d_in[1];
    // d_in[2] edge_attr: ignored (GATConv has no edge_dim)
    const float* W1     = (const float*)d_in[3];
    const float* a_src1 = (const float*)d_in[4];
    const float* a_dst1 = (const float*)d_in[5];
    const float* b1     = (const float*)d_in[6];
    const float* W2     = (const float*)d_in[7];
    const float* a_src2 = (const float*)d_in[8];
    const float* a_dst2 = (const float*)d_in[9];
    const float* b2     = (const float*)d_in[10];
    const float* fc1w   = (const float*)d_in[11];
    const float* fc1b   = (const float*)d_in[12];
    const float* fc2w   = (const float*)d_in[13];
    const float* fc2b   = (const float*)d_in[14];
    const float* fc3w   = (const float*)d_in[15];
    const float* fc3b   = (const float*)d_in[16];
    float* out = (float*)d_out;

    // ---- workspace carve-up ----
    char* ws = (char*)d_ws;
    size_t o = 0;
    auto take = [&](size_t bytes) -> char* {
        char* p = ws + o;
        o = (o + bytes + 255) & ~(size_t)255;
        return p;
    };
    // zero-initialized block (indeg + per-barrier counters) — re-zeroed every replay
    int*    indeg  = (int*)take(NN * 4);
    int*    barcnt = (int*)take(8 * 4);
    size_t zero_bytes = o;
    // rest
    float*  as2    = (float*)take(NN * 4);
    float*  ad2    = (float*)take(NN * 4);
    int*    srcELL = (int*)take((size_t)NN * ELLW * 4);
    float*  as1    = (float*)take((size_t)NN * HC1 * 4);
    float*  ad1    = (float*)take((size_t)NN * HC1 * 4);
    bf16_t* w1sT   = (bf16_t*)take((size_t)16 * F_IN * 2);
    bf16_t* x_bf   = (bf16_t*)take((size_t)NN * F_IN * 2);
    bf16_t* xagg   = (bf16_t*)take((size_t)NN * HC1 * F_IN * 2);   // [N][H][128]
    bf16_t* Wt1    = (bf16_t*)take((size_t)F_IN * 4096 * 2);       // [4096][128]
    bf16_t* Wt2    = (bf16_t*)take((size_t)4096 * 512 * 2);        // [512][4096]
    bf16_t* fc1wt  = (bf16_t*)take((size_t)4096 * 512 * 2);        // [512][4096]
    bf16_t* out1bf = (bf16_t*)take((size_t)NN * 4096 * 2);         // GAT1 out (bf16)
    bf16_t* h2bf   = (bf16_t*)take((size_t)NN * 512 * 2);          // GEMM2 out (bf16)
    bf16_t* out2bf = (bf16_t*)take((size_t)NN * 512 * 2);          // GAT2 out (bf16)
    bf16_t* part   = (bf16_t*)take((size_t)4 * NN * 512 * 2);      // split-K partials (bf16, 16 MB)

    hipMemsetAsync(d_ws, 0, zero_bytes, stream);

    // ---- P0: prep (separate dispatch; stream ordering = full coherence into mega) ----
    prep_k<<<dim3(5296), dim3(256), 0, stream>>>(x, W1, W2, fc1w, a_src1, a_dst1, ei,
                                                 x_bf, Wt1, Wt2, fc1wt, w1sT,
                                                 srcELL, indeg);

    // ---- P1..P8 fused persistent kernel (regular launch; co-residency by construction) ----
    mega2_k<<<dim3(GRID), dim3(256), 0, stream>>>(
        x_bf, w1sT, as1, ad1, indeg, srcELL, xagg,
        Wt1, b1, out1bf, Wt2, part,
        a_src2, a_dst2, h2bf, as2, ad2, b2, out2bf,
        fc1wt, fc1b, fc2w, fc2b, fc3w, fc3b, out, barcnt);
}

// Round 6
// 514.327 us; speedup vs baseline: 1.8739x; 1.8739x over previous
//
#include <hip/hip_runtime.h>
#include <cstdint>
#include <cstddef>

// Problem constants (fixed by the reference)
#define NN    4096      // nodes
#define E0C   32768     // raw edges
#define ETC   (E0C+NN)  // edges + self loops = 36864
#define HC1   8         // heads layer1
#define CC    512       // channels per head (both layers)
#define F_IN  128
#define NEG_SLOPE_F 0.2f
#define ELLW  64        // ELL width; max in-degree ~Poisson(9) << 64
#define GRID  512       // persistent blocks: 2/CU on 256 CUs (guaranteed by launch_bounds+LDS)

typedef __bf16 bf16_t;
typedef __bf16 bf16x8 __attribute__((ext_vector_type(8)));
typedef __bf16 bf16x4 __attribute__((ext_vector_type(4)));
typedef __bf16 bf16x2 __attribute__((ext_vector_type(2)));
typedef float  f32x4  __attribute__((ext_vector_type(4)));

// async global->LDS, 16B per lane; LDS dest must be linear (wave-uniform base + lane*16)
__device__ __forceinline__ void gload_lds16(const void* g, void* l) {
    __builtin_amdgcn_global_load_lds(
        (const __attribute__((address_space(1))) void*)g,
        (__attribute__((address_space(3))) void*)l, 16, 0, 0);
}

// ---- grid barrier, fixed protocol ----
// Round-5 bug: ACQUIRE polling -> every poll carries a cache invalidate; 512
// spinning blocks invalidated L2 continuously -> whole device latency-bound
// (855us @ MfmaUtil 1.1%). Fix: RELEASE arrive (one wbl2 publish), RELAXED
// poll (agent atomic load reads coherent point, no invalidate), ONE acquire
// fence at exit. Occasional ACQUIRE poll (1/64) as livelock insurance.
__device__ __forceinline__ void gbar(int* cnts, int idx) {
    __syncthreads();          // all waves' stores drained (vmcnt 0) before arrive
    if (threadIdx.x == 0) {
        __hip_atomic_fetch_add(&cnts[idx], 1, __ATOMIC_RELEASE, __HIP_MEMORY_SCOPE_AGENT);
        int polls = 0;
        for (;;) {
            int v = ((++polls & 63) == 0)
                ? __hip_atomic_load(&cnts[idx], __ATOMIC_ACQUIRE, __HIP_MEMORY_SCOPE_AGENT)
                : __hip_atomic_load(&cnts[idx], __ATOMIC_RELAXED, __HIP_MEMORY_SCOPE_AGENT);
            if (v >= GRID) break;
            __builtin_amdgcn_s_sleep(32);
        }
        __threadfence();      // single acquire-side fence: this CU sees others' data
    }
    __syncthreads();
}

// ---------- prep: region-dispatched standalone kernel (verbatim known-good) ----------
__device__ __forceinline__ void tcast_body(const float* __restrict__ W, bf16_t* __restrict__ Wt,
                                           int K, int N, int bx, int by)
{
    __shared__ float t[32][33];
    int bn = bx * 32, bk = by * 32;
    int tx = threadIdx.x & 31, ty = threadIdx.x >> 5;
    #pragma unroll
    for (int i = 0; i < 32; i += 8)
        t[ty + i][tx] = W[(size_t)(bk + ty + i) * N + bn + tx];
    __syncthreads();
    #pragma unroll
    for (int i = 0; i < 32; i += 8)
        Wt[(size_t)(bn + ty + i) * K + bk + tx] = (bf16_t)t[tx][ty + i];
}

__global__ __launch_bounds__(256) void prep_k(const float* __restrict__ x,
    const float* __restrict__ W1, const float* __restrict__ W2,
    const float* __restrict__ fc1w, const float* __restrict__ a_src1,
    const float* __restrict__ a_dst1, const int* __restrict__ ei,
    bf16_t* __restrict__ x_bf, bf16_t* __restrict__ Wt1, bf16_t* __restrict__ Wt2,
    bf16_t* __restrict__ fc1wt, bf16_t* __restrict__ w1sT,
    int* __restrict__ srcELL, int* __restrict__ indeg)
{
    const int b = blockIdx.x;
    if (b < 512) {
        int i = (b * 256 + threadIdx.x) * 4;
        float4 v = *(const float4*)&x[i];
        bf16x4 o;
        o[0] = (bf16_t)v.x; o[1] = (bf16_t)v.y; o[2] = (bf16_t)v.z; o[3] = (bf16_t)v.w;
        *(bf16x4*)&x_bf[i] = o;
    } else if (b < 1024) {
        int bl = b - 512;
        tcast_body(W1, Wt1, F_IN, 4096, bl % 128, bl / 128);
    } else if (b < 3072) {
        int bl = b - 1024;
        tcast_body(W2, Wt2, 4096, 512, bl % 16, bl / 16);
    } else if (b < 5120) {
        int bl = b - 3072;
        tcast_body(fc1w, fc1wt, 4096, 512, bl % 16, bl / 16);
    } else if (b < 5152) {
        int bl = b - 5120;                     // 0..31
        int wave = threadIdx.x >> 6, lane = threadIdx.x & 63;
        int k = bl * 4 + wave;                 // 0..127
        int hd = lane >> 3;
        int co = (lane & 7) * 64;
        const float* wrow = W1 + (size_t)k * (HC1 * CC) + hd * CC + co;
        const float* vs = a_src1 + hd * CC + co;
        const float* vd = a_dst1 + hd * CC + co;
        float s = 0.f, d = 0.f;
        #pragma unroll 4
        for (int t = 0; t < 64; ++t) {
            float w = wrow[t];
            s += w * vs[t];
            d += w * vd[t];
        }
        #pragma unroll
        for (int off = 1; off < 8; off <<= 1) {
            s += __shfl_xor(s, off);
            d += __shfl_xor(d, off);
        }
        if ((lane & 7) == 0) {
            w1sT[hd * F_IN + k]       = (bf16_t)s;
            w1sT[(hd + 8) * F_IN + k] = (bf16_t)d;
        }
    } else {
        int e = (b - 5152) * 256 + threadIdx.x;
        if (e < ETC) {
            int s, d;
            if (e < E0C) { s = ei[e]; d = ei[E0C + e]; }
            else         { s = e - E0C; d = s; }
            int pos = atomicAdd(&indeg[d], 1);
            if (pos < ELLW) srcELL[d * ELLW + pos] = s;
        }
    }
}

// ---------- phase bodies (verbatim from passed rounds) ----------
__device__ __forceinline__ void alpha1_body(int vb, const bf16_t* __restrict__ x_bf,
    const bf16_t* __restrict__ w1sT, float* __restrict__ as1, float* __restrict__ ad1)
{
    const int wave = threadIdx.x >> 6, lane = threadIdx.x & 63;
    const int bm = vb * 64 + wave * 16;
    const int lm = lane & 15, quad = lane >> 4;
    f32x4 acc = {};
    #pragma unroll
    for (int k0 = 0; k0 < F_IN; k0 += 32) {
        bf16x8 af = *(const bf16x8*)&x_bf[(size_t)(bm + lm) * F_IN + k0 + quad * 8];
        bf16x8 bf = *(const bf16x8*)&w1sT[lm * F_IN + k0 + quad * 8];
        acc = __builtin_amdgcn_mfma_f32_16x16x32_bf16(af, bf, acc, 0, 0, 0);
    }
    #pragma unroll
    for (int r = 0; r < 4; ++r) {
        int n = bm + quad * 4 + r;
        if (lm < 8) as1[n * HC1 + lm] = acc[r];
        else        ad1[n * HC1 + (lm - 8)] = acc[r];
    }
}

__device__ __forceinline__ void aggx_body(int vb, const bf16_t* __restrict__ x_bf,
    const float* __restrict__ as1, const float* __restrict__ ad1,
    const int* __restrict__ indeg, const int* __restrict__ srcELL,
    bf16_t* __restrict__ xagg)
{
    const int wave = threadIdx.x >> 6, lane = threadIdx.x & 63;
    const int n = vb * 4 + wave;
    const int c = lane * 2;
    const int deg = min(indeg[n], ELLW);

    int vsrc = 0;
    float vp[HC1] = {};
    if (lane < deg) {
        vsrc = srcELL[n * ELLW + lane];
        #pragma unroll
        for (int hd = 0; hd < HC1; ++hd) {
            float v = as1[vsrc * HC1 + hd] + ad1[n * HC1 + hd];
            v = (v > 0.f) ? v : NEG_SLOPE_F * v;
            vp[hd] = __expf(v);
        }
    }
    #pragma unroll
    for (int hd = 0; hd < HC1; ++hd) {
        float dsum = vp[hd];
        #pragma unroll
        for (int off = 1; off < 64; off <<= 1)
            dsum += __shfl_xor(dsum, off);
        vp[hd] *= 1.f / dsum;
    }

    float acc[HC1][2] = {};
    int ii = 0;
    for (; ii + 2 <= deg; ii += 2) {
        int s0 = __shfl(vsrc, ii), s1 = __shfl(vsrc, ii + 1);
        bf16x2 r0 = *(const bf16x2*)&x_bf[(size_t)s0 * F_IN + c];
        bf16x2 r1 = *(const bf16x2*)&x_bf[(size_t)s1 * F_IN + c];
        float f00 = (float)r0[0], f01 = (float)r0[1];
        float f10 = (float)r1[0], f11 = (float)r1[1];
        #pragma unroll
        for (int hd = 0; hd < HC1; ++hd) {
            float a0 = __shfl(vp[hd], ii);
            float a1 = __shfl(vp[hd], ii + 1);
            acc[hd][0] += a0 * f00 + a1 * f10;
            acc[hd][1] += a0 * f01 + a1 * f11;
        }
    }
    for (; ii < deg; ++ii) {
        int s = __shfl(vsrc, ii);
        bf16x2 rv = *(const bf16x2*)&x_bf[(size_t)s * F_IN + c];
        float r0 = (float)rv[0], r1 = (float)rv[1];
        #pragma unroll
        for (int hd = 0; hd < HC1; ++hd) {
            float al = __shfl(vp[hd], ii);
            acc[hd][0] += al * r0;
            acc[hd][1] += al * r1;
        }
    }
    #pragma unroll
    for (int hd = 0; hd < HC1; ++hd) {
        bf16x2 o;
        o[0] = (bf16_t)acc[hd][0];
        o[1] = (bf16_t)acc[hd][1];
        *(bf16x2*)&xagg[((size_t)n * HC1 + hd) * F_IN + c] = o;
    }
}

__device__ __forceinline__ void gemmh_body(int bxi, int byi, int hd,
    const bf16_t* __restrict__ xagg, const bf16_t* __restrict__ Wt1,
    const float* __restrict__ b1, bf16_t* __restrict__ out1,
    bf16_t (*As)[4096], bf16_t (*Bs)[4096])
{
    const int tid = threadIdx.x;
    const int bm = bxi * 128, bn = byi * 128;

    const int wave = tid >> 6, lane = tid & 63;
    const int wm = wave >> 1, wn = wave & 1;
    const int lm = lane & 15, quad = lane >> 4;

    const int sr = tid >> 2;
    const int kg = tid & 3;
    const int swcol = (kg ^ (sr & 3)) * 8;

    const bf16_t* Aptr = xagg + ((size_t)(bm + sr) * HC1 + hd) * F_IN + swcol;
    const bf16_t* Bptr = Wt1 + (size_t)(hd * CC + bn + sr) * F_IN + swcol;
    const size_t raskip = (size_t)64 * HC1 * F_IN;
    const size_t rbskip = (size_t)64 * F_IN;

    const int fswz = ((quad ^ (lm & 3)) * 8);

    f32x4 acc[4][4] = {};

    gload_lds16(Aptr,          &As[0][tid * 8]);
    gload_lds16(Aptr + raskip, &As[0][2048 + tid * 8]);
    gload_lds16(Bptr,          &Bs[0][tid * 8]);
    gload_lds16(Bptr + rbskip, &Bs[0][2048 + tid * 8]);
    __syncthreads();

    int cur = 0;
    for (int k0 = 0; k0 < F_IN; k0 += 32) {
        if (k0 + 32 < F_IN) {
            const bf16_t* An = Aptr + (k0 + 32);
            const bf16_t* Bn = Bptr + (k0 + 32);
            gload_lds16(An,          &As[cur ^ 1][tid * 8]);
            gload_lds16(An + raskip, &As[cur ^ 1][2048 + tid * 8]);
            gload_lds16(Bn,          &Bs[cur ^ 1][tid * 8]);
            gload_lds16(Bn + rbskip, &Bs[cur ^ 1][2048 + tid * 8]);
        }
        const bf16_t* Ac = As[cur];
        const bf16_t* Bc = Bs[cur];
        bf16x8 af[4], bfr[4];
        #pragma unroll
        for (int i = 0; i < 4; ++i) {
            af[i]  = *(const bf16x8*)&Ac[(wm * 64 + i * 16 + lm) * 32 + fswz];
            bfr[i] = *(const bf16x8*)&Bc[(wn * 64 + i * 16 + lm) * 32 + fswz];
        }
        #pragma unroll
        for (int mt = 0; mt < 4; ++mt)
            #pragma unroll
            for (int nt = 0; nt < 4; ++nt)
                acc[mt][nt] = __builtin_amdgcn_mfma_f32_16x16x32_bf16(bfr[nt], af[mt], acc[mt][nt], 0, 0, 0);
        __syncthreads();
        cur ^= 1;
    }

    #pragma unroll
    for (int mt = 0; mt < 4; ++mt) {
        int gr = bm + wm * 64 + mt * 16 + lm;
        bf16_t* orow = out1 + (size_t)gr * 4096 + hd * CC;
        #pragma unroll
        for (int nt = 0; nt < 4; ++nt) {
            int gc = bn + wn * 64 + nt * 16 + quad * 4;
            f32x4 bv = *(const f32x4*)&b1[hd * CC + gc];
            bf16x4 o;
            #pragma unroll
            for (int r = 0; r < 4; ++r)
                o[r] = (bf16_t)fmaxf(acc[mt][nt][r] + bv[r], 0.f);
            *(bf16x4*)&orow[gc] = o;
        }
    }
}

__device__ __forceinline__ void gemm128s_body(int bxi, int byi, int kz,
    const bf16_t* __restrict__ A, const bf16_t* __restrict__ Bt,
    bf16_t* __restrict__ Cpart, int M, int N, int K, int Kc,
    bf16_t (*As)[4096], bf16_t (*Bs)[4096])
{
    const int tid = threadIdx.x;
    const int bm = bxi * 128, bn = byi * 128;
    const int k_beg = kz * Kc;
    const int k_end = k_beg + Kc;

    const int wave = tid >> 6, lane = tid & 63;
    const int wm = wave >> 1, wn = wave & 1;
    const int lm = lane & 15, quad = lane >> 4;

    const int sr = tid >> 2;
    const int kg = tid & 3;
    const int swcol = (kg ^ (sr & 3)) * 8;

    const bf16_t* Aptr = A + (size_t)(bm + sr) * K + k_beg + swcol;
    const bf16_t* Bptr = Bt + (size_t)(bn + sr) * K + k_beg + swcol;
    const size_t rowskip = (size_t)64 * K;

    const int fswz = ((quad ^ (lm & 3)) * 8);

    f32x4 acc[4][4] = {};

    gload_lds16(Aptr,           &As[0][tid * 8]);
    gload_lds16(Aptr + rowskip, &As[0][2048 + tid * 8]);
    gload_lds16(Bptr,           &Bs[0][tid * 8]);
    gload_lds16(Bptr + rowskip, &Bs[0][2048 + tid * 8]);
    __syncthreads();

    int cur = 0;
    for (int k0 = k_beg; k0 < k_end; k0 += 32) {
        if (k0 + 32 < k_end) {
            const bf16_t* An = Aptr + (k0 + 32 - k_beg);
            const bf16_t* Bn = Bptr + (k0 + 32 - k_beg);
            gload_lds16(An,           &As[cur ^ 1][tid * 8]);
            gload_lds16(An + rowskip, &As[cur ^ 1][2048 + tid * 8]);
            gload_lds16(Bn,           &Bs[cur ^ 1][tid * 8]);
            gload_lds16(Bn + rowskip, &Bs[cur ^ 1][2048 + tid * 8]);
        }
        const bf16_t* Ac = As[cur];
        const bf16_t* Bc = Bs[cur];
        bf16x8 af[4], bfr[4];
        #pragma unroll
        for (int i = 0; i < 4; ++i) {
            af[i]  = *(const bf16x8*)&Ac[(wm * 64 + i * 16 + lm) * 32 + fswz];
            bfr[i] = *(const bf16x8*)&Bc[(wn * 64 + i * 16 + lm) * 32 + fswz];
        }
        #pragma unroll
        for (int mt = 0; mt < 4; ++mt)
            #pragma unroll
            for (int nt = 0; nt < 4; ++nt)
                acc[mt][nt] = __builtin_amdgcn_mfma_f32_16x16x32_bf16(bfr[nt], af[mt], acc[mt][nt], 0, 0, 0);
        __syncthreads();
        cur ^= 1;
    }

    bf16_t* P = Cpart + (size_t)kz * M * N;
    #pragma unroll
    for (int mt = 0; mt < 4; ++mt) {
        int gr = bm + wm * 64 + mt * 16 + lm;
        #pragma unroll
        for (int nt = 0; nt < 4; ++nt) {
            int gc = bn + wn * 64 + nt * 16 + quad * 4;
            bf16x4 o;
            #pragma unroll
            for (int r = 0; r < 4; ++r)
                o[r] = (bf16_t)acc[mt][nt][r];
            *(bf16x4*)&P[(size_t)gr * N + gc] = o;
        }
    }
}

__device__ __forceinline__ void reduce_body(int vb, const bf16_t* __restrict__ P,
    const float* __restrict__ a_s, const float* __restrict__ a_d,
    bf16_t* __restrict__ h2bf, float* __restrict__ as2, float* __restrict__ ad2)
{
    __shared__ float sred[4][2];
    const int t = threadIdx.x;
    const int i = vb * 1024 + t * 4;
    f32x4 s = {};
    #pragma unroll
    for (int z = 0; z < 4; ++z) {
        bf16x4 pv = *(const bf16x4*)&P[(size_t)z * NN * CC + i];
        #pragma unroll
        for (int j = 0; j < 4; ++j) s[j] += (float)pv[j];
    }
    bf16x4 o;
    #pragma unroll
    for (int j = 0; j < 4; ++j) o[j] = (bf16_t)s[j];
    *(bf16x4*)&h2bf[i] = o;

    const int c = (t & 127) * 4;
    f32x4 va = *(const f32x4*)&a_s[c];
    f32x4 vd = *(const f32x4*)&a_d[c];
    float ls = s[0]*va[0] + s[1]*va[1] + s[2]*va[2] + s[3]*va[3];
    float ld = s[0]*vd[0] + s[1]*vd[1] + s[2]*vd[2] + s[3]*vd[3];
    #pragma unroll
    for (int off = 32; off > 0; off >>= 1) {
        ls += __shfl_down(ls, off);
        ld += __shfl_down(ld, off);
    }
    const int wave = t >> 6, lane = t & 63;
    if (lane == 0) { sred[wave][0] = ls; sred[wave][1] = ld; }
    __syncthreads();
    if (t == 0) {
        as2[vb * 2]     = sred[0][0] + sred[1][0];
        ad2[vb * 2]     = sred[0][1] + sred[1][1];
    }
    if (t == 128) {
        as2[vb * 2 + 1] = sred[2][0] + sred[3][0];
        ad2[vb * 2 + 1] = sred[2][1] + sred[3][1];
    }
    __syncthreads();   // sred reuse across vb iterations
}

__device__ __forceinline__ void agg2_body(int vb, const bf16_t* __restrict__ hbuf,
    const float* __restrict__ as, const float* __restrict__ ad,
    const int* __restrict__ indeg, const int* __restrict__ srcELL,
    const float* __restrict__ bias, bf16_t* __restrict__ outb)
{
    const int wave = threadIdx.x >> 6, lane = threadIdx.x & 63;
    const int n = vb * 4 + wave;
    const int c = lane * 8;

    const int deg = min(indeg[n], ELLW);
    const float adn = ad[n];

    int vsrc = 0; float vp = 0.f;
    if (lane < deg) {
        vsrc = srcELL[n * ELLW + lane];
        float v = as[vsrc] + adn;
        v = (v > 0.f) ? v : NEG_SLOPE_F * v;
        vp = __expf(v);
    }
    float denom = vp;
    #pragma unroll
    for (int off = 1; off < 64; off <<= 1)
        denom += __shfl_xor(denom, off);
    vp *= 1.f / denom;

    float acc[8] = {};
    int ii = 0;
    for (; ii + 4 <= deg; ii += 4) {
        int s0 = __shfl(vsrc, ii),     s1 = __shfl(vsrc, ii + 1);
        int s2 = __shfl(vsrc, ii + 2), s3 = __shfl(vsrc, ii + 3);
        float a0 = __shfl(vp, ii),     a1 = __shfl(vp, ii + 1);
        float a2 = __shfl(vp, ii + 2), a3 = __shfl(vp, ii + 3);
        bf16x8 r0 = *(const bf16x8*)&hbuf[(size_t)s0 * CC + c];
        bf16x8 r1 = *(const bf16x8*)&hbuf[(size_t)s1 * CC + c];
        bf16x8 r2 = *(const bf16x8*)&hbuf[(size_t)s2 * CC + c];
        bf16x8 r3 = *(const bf16x8*)&hbuf[(size_t)s3 * CC + c];
        #pragma unroll
        for (int j = 0; j < 8; ++j) {
            acc[j] += a0 * (float)r0[j];
            acc[j] += a1 * (float)r1[j];
            acc[j] += a2 * (float)r2[j];
            acc[j] += a3 * (float)r3[j];
        }
    }
    for (; ii < deg; ++ii) {
        int s = __shfl(vsrc, ii);
        float al = __shfl(vp, ii);
        bf16x8 rv = *(const bf16x8*)&hbuf[(size_t)s * CC + c];
        #pragma unroll
        for (int j = 0; j < 8; ++j)
            acc[j] += al * (float)rv[j];
    }
    size_t ob = (size_t)n * CC;
    bf16x8 o;
    #pragma unroll
    for (int j = 0; j < 8; ++j)
        o[j] = (bf16_t)fmaxf(acc[j] + bias[c + j], 0.f);
    *(bf16x8*)&outb[ob + c] = o;
}

__device__ __forceinline__ void tail_body(int m, const bf16_t* __restrict__ P,
    const float* __restrict__ fc1b, const float* __restrict__ fc2w,
    const float* __restrict__ fc2b, const float* __restrict__ fc3w,
    const float* __restrict__ fc3b, float* __restrict__ out)
{
    __shared__ float sA[512];
    __shared__ float sF2[128];
    const int t = threadIdx.x;
    const int MN = 512 * 512;
    #pragma unroll
    for (int i = 0; i < 2; ++i) {
        int c = t + i * 256;
        float v = 0.f;
        #pragma unroll
        for (int z = 0; z < 16; ++z)
            v += (float)P[(size_t)z * MN + (size_t)m * 512 + c];
        sA[c] = fmaxf(v + fc1b[c], 0.f);
    }
    __syncthreads();
    if (t < 128) {
        float a0 = 0.f, a1 = 0.f, a2 = 0.f, a3 = 0.f;
        #pragma unroll 4
        for (int k = 0; k < 512; k += 4) {
            a0 += sA[k + 0] * fc2w[(k + 0) * 128 + t];
            a1 += sA[k + 1] * fc2w[(k + 1) * 128 + t];
            a2 += sA[k + 2] * fc2w[(k + 2) * 128 + t];
            a3 += sA[k + 3] * fc2w[(k + 3) * 128 + t];
        }
        sF2[t] = fmaxf((a0 + a1) + (a2 + a3) + fc2b[t], 0.f);
    }
    __syncthreads();
    if (t < 10) {
        float o = fc3b[t];
        #pragma unroll 4
        for (int k = 0; k < 128; ++k)
            o += sF2[k] * fc3w[k * 10 + t];
        out[(size_t)m * 10 + t] = o;
    }
    __syncthreads();   // sA/sF2 reuse across vb iterations
}

// ---------- persistent kernel: phases P1..P8, 7 grid barriers, REGULAR launch ----------
__global__ __launch_bounds__(256, 2) void mega2_k(
    const bf16_t* x_bf, const bf16_t* w1sT, float* as1, float* ad1,
    const int* indeg, const int* srcELL, bf16_t* xagg,
    const bf16_t* Wt1, const float* b1, bf16_t* out1bf,
    const bf16_t* Wt2, bf16_t* part,
    const float* a_src2, const float* a_dst2, bf16_t* h2bf, float* as2, float* ad2,
    const float* b2, bf16_t* out2bf,
    const bf16_t* fc1wt, const float* fc1b,
    const float* fc2w, const float* fc2b, const float* fc3w, const float* fc3b,
    float* out, int* barcnt)
{
    __shared__ bf16_t sAs[2][4096];   // shared by all GEMM phases
    __shared__ bf16_t sBs[2][4096];
    const int bid = blockIdx.x;

    // P1: alpha1 (64 vb)
    for (int vb = bid; vb < 64; vb += GRID)
        alpha1_body(vb, x_bf, w1sT, as1, ad1);
    gbar(barcnt, 0);

    // P2: aggx (1024 vb)
    for (int vb = bid; vb < 1024; vb += GRID)
        aggx_body(vb, x_bf, as1, ad1, indeg, srcELL, xagg);
    gbar(barcnt, 1);

    // P3: gemmh (1024 vb): decode (32,4,8)
    for (int vb = bid; vb < 1024; vb += GRID)
        gemmh_body(vb & 31, (vb >> 5) & 3, vb >> 7, xagg, Wt1, b1, out1bf, sAs, sBs);
    gbar(barcnt, 2);

    // P4: layer-2 GEMM (512 vb): decode (32,4,4), M=4096,N=512,K=4096,Kc=1024
    for (int vb = bid; vb < 512; vb += GRID)
        gemm128s_body(vb & 31, (vb >> 5) & 3, vb >> 7,
                      out1bf, Wt2, part, 4096, 512, 4096, 1024, sAs, sBs);
    gbar(barcnt, 3);

    // P5: reduce h2 + alpha2 (2048 vb)
    for (int vb = bid; vb < 2048; vb += GRID)
        reduce_body(vb, part, a_src2, a_dst2, h2bf, as2, ad2);
    gbar(barcnt, 4);

    // P6: aggregate2 (1024 vb)
    for (int vb = bid; vb < 1024; vb += GRID)
        agg2_body(vb, h2bf, as2, ad2, indeg, srcELL, b2, out2bf);
    gbar(barcnt, 5);

    // P7: fc1 GEMM (256 vb): decode (4,4,16), M=512,N=512,K=4096,Kc=256
    for (int vb = bid; vb < 256; vb += GRID)
        gemm128s_body(vb & 3, (vb >> 2) & 3, vb >> 4,
                      out2bf, fc1wt, part, 512, 512, 4096, 256, sAs, sBs);
    gbar(barcnt, 6);

    // P8: tail (512 vb)
    for (int vb = bid; vb < 512; vb += GRID)
        tail_body(vb, part, fc1b, fc2w, fc2b, fc3w, fc3b, out);
}

extern "C" void kernel_launch(void* const* d_in, const int* in_sizes, int n_in,
                              void* d_out, int out_size, void* d_ws, size_t ws_size,
                              hipStream_t stream) {
    const float* x      = (const float*)d_in[0];
    const int*   ei     = (const int*)d_in[1];
    // d_in[2] edge_attr: ignored (GATConv has no edge_dim)
    const float* W1     = (const float*)d_in[3];
    const float* a_src1 = (const float*)d_in[4];
    const float* a_dst1 = (const float*)d_in[5];
    const float* b1     = (const float*)d_in[6];
    const float* W2     = (const float*)d_in[7];
    const float* a_src2 = (const float*)d_in[8];
    const float* a_dst2 = (const float*)d_in[9];
    const float* b2     = (const float*)d_in[10];
    const float* fc1w   = (const float*)d_in[11];
    const float* fc1b   = (const float*)d_in[12];
    const float* fc2w   = (const float*)d_in[13];
    const float* fc2b   = (const float*)d_in[14];
    const float* fc3w   = (const float*)d_in[15];
    const float* fc3b   = (const float*)d_in[16];
    float* out = (float*)d_out;

    // ---- workspace carve-up ----
    char* ws = (char*)d_ws;
    size_t o = 0;
    auto take = [&](size_t bytes) -> char* {
        char* p = ws + o;
        o = (o + bytes + 255) & ~(size_t)255;
        return p;
    };
    // zero-initialized block (indeg + per-barrier counters) — re-zeroed every replay
    int*    indeg  = (int*)take(NN * 4);
    int*    barcnt = (int*)take(8 * 4);
    size_t zero_bytes = o;
    // rest
    float*  as2    = (float*)take(NN * 4);
    float*  ad2    = (float*)take(NN * 4);
    int*    srcELL = (int*)take((size_t)NN * ELLW * 4);
    float*  as1    = (float*)take((size_t)NN * HC1 * 4);
    float*  ad1    = (float*)take((size_t)NN * HC1 * 4);
    bf16_t* w1sT   = (bf16_t*)take((size_t)16 * F_IN * 2);
    bf16_t* x_bf   = (bf16_t*)take((size_t)NN * F_IN * 2);
    bf16_t* xagg   = (bf16_t*)take((size_t)NN * HC1 * F_IN * 2);   // [N][H][128]
    bf16_t* Wt1    = (bf16_t*)take((size_t)F_IN * 4096 * 2);       // [4096][128]
    bf16_t* Wt2    = (bf16_t*)take((size_t)4096 * 512 * 2);        // [512][4096]
    bf16_t* fc1wt  = (bf16_t*)take((size_t)4096 * 512 * 2);        // [512][4096]
    bf16_t* out1bf = (bf16_t*)take((size_t)NN * 4096 * 2);         // GAT1 out (bf16)
    bf16_t* h2bf   = (bf16_t*)take((size_t)NN * 512 * 2);          // GEMM2 out (bf16)
    bf16_t* out2bf = (bf16_t*)take((size_t)NN * 512 * 2);          // GAT2 out (bf16)
    bf16_t* part   = (bf16_t*)take((size_t)4 * NN * 512 * 2);      // split-K partials (bf16, 16 MB)

    hipMemsetAsync(d_ws, 0, zero_bytes, stream);

    // ---- P0: prep (separate dispatch; stream ordering = full coherence into mega) ----
    prep_k<<<dim3(5296), dim3(256), 0, stream>>>(x, W1, W2, fc1w, a_src1, a_dst1, ei,
                                                 x_bf, Wt1, Wt2, fc1wt, w1sT,
                                                 srcELL, indeg);

    // ---- P1..P8 fused persistent kernel (regular launch; co-residency by construction) ----
    mega2_k<<<dim3(GRID), dim3(256), 0, stream>>>(
        x_bf, w1sT, as1, ad1, indeg, srcELL, xagg,
        Wt1, b1, out1bf, Wt2, part,
        a_src2, a_dst2, h2bf, as2, ad2, b2, out2bf,
        fc1wt, fc1b, fc2w, fc2b, fc3w, fc3b, out, barcnt);
}

// Round 8
// 205.042 us; speedup vs baseline: 4.7005x; 2.5084x over previous
//
#include <hip/hip_runtime.h>
#include <cstdint>
#include <cstddef>

// Problem constants (fixed by the reference)
#define NN    4096      // nodes
#define E0C   32768     // raw edges
#define ETC   (E0C+NN)  // edges + self loops = 36864
#define HC1   8         // heads layer1
#define CC    512       // channels per head (both layers)
#define F_IN  128
#define NEG_SLOPE_F 0.2f
#define ELLW  64        // ELL width; max in-degree ~Poisson(9) << 64

typedef __bf16 bf16_t;
typedef __bf16 bf16x8 __attribute__((ext_vector_type(8)));
typedef __bf16 bf16x4 __attribute__((ext_vector_type(4)));
typedef __bf16 bf16x2 __attribute__((ext_vector_type(2)));
typedef float  f32x4  __attribute__((ext_vector_type(4)));

// async global->LDS, 16B per lane; LDS dest must be linear (wave-uniform base + lane*16)
__device__ __forceinline__ void gload_lds16(const void* g, void* l) {
    __builtin_amdgcn_global_load_lds(
        (const __attribute__((address_space(1))) void*)g,
        (__attribute__((address_space(3))) void*)l, 16, 0, 0);
}

// ---------- fused prep: region-dispatched ----------
__device__ __forceinline__ void tcast_body(const float* __restrict__ W, bf16_t* __restrict__ Wt,
                                           int K, int N, int bx, int by)
{
    __shared__ float t[32][33];
    int bn = bx * 32, bk = by * 32;
    int tx = threadIdx.x & 31, ty = threadIdx.x >> 5;
    #pragma unroll
    for (int i = 0; i < 32; i += 8)
        t[ty + i][tx] = W[(size_t)(bk + ty + i) * N + bn + tx];
    __syncthreads();
    #pragma unroll
    for (int i = 0; i < 32; i += 8)
        Wt[(size_t)(bn + ty + i) * K + bk + tx] = (bf16_t)t[tx][ty + i];
}

__global__ __launch_bounds__(256) void prep_k(const float* __restrict__ x,
    const float* __restrict__ W1, const float* __restrict__ W2,
    const float* __restrict__ fc1w, const float* __restrict__ a_src1,
    const float* __restrict__ a_dst1, const int* __restrict__ ei,
    bf16_t* __restrict__ x_bf, bf16_t* __restrict__ Wt1, bf16_t* __restrict__ Wt2,
    bf16_t* __restrict__ fc1wt, bf16_t* __restrict__ w1sT,
    int* __restrict__ srcELL, int* __restrict__ indeg)
{
    const int b = blockIdx.x;
    if (b < 512) {
        int i = (b * 256 + threadIdx.x) * 4;
        float4 v = *(const float4*)&x[i];
        bf16x4 o;
        o[0] = (bf16_t)v.x; o[1] = (bf16_t)v.y; o[2] = (bf16_t)v.z; o[3] = (bf16_t)v.w;
        *(bf16x4*)&x_bf[i] = o;
    } else if (b < 1024) {
        int bl = b - 512;
        tcast_body(W1, Wt1, F_IN, 4096, bl % 128, bl / 128);
    } else if (b < 3072) {
        int bl = b - 1024;
        tcast_body(W2, Wt2, 4096, 512, bl % 16, bl / 16);
    } else if (b < 5120) {
        int bl = b - 3072;
        tcast_body(fc1w, fc1wt, 4096, 512, bl % 16, bl / 16);
    } else if (b < 5152) {
        int bl = b - 5120;                     // 0..31
        int wave = threadIdx.x >> 6, lane = threadIdx.x & 63;
        int k = bl * 4 + wave;                 // 0..127
        int hd = lane >> 3;
        int co = (lane & 7) * 64;
        const float* wrow = W1 + (size_t)k * (HC1 * CC) + hd * CC + co;
        const float* vs = a_src1 + hd * CC + co;
        const float* vd = a_dst1 + hd * CC + co;
        float s = 0.f, d = 0.f;
        #pragma unroll 4
        for (int t = 0; t < 64; ++t) {
            float w = wrow[t];
            s += w * vs[t];
            d += w * vd[t];
        }
        #pragma unroll
        for (int off = 1; off < 8; off <<= 1) {
            s += __shfl_xor(s, off);
            d += __shfl_xor(d, off);
        }
        if ((lane & 7) == 0) {
            w1sT[hd * F_IN + k]       = (bf16_t)s;
            w1sT[(hd + 8) * F_IN + k] = (bf16_t)d;
        }
    } else {
        int e = (b - 5152) * 256 + threadIdx.x;
        if (e < ETC) {
            int s, d;
            if (e < E0C) { s = ei[e]; d = ei[E0C + e]; }
            else         { s = e - E0C; d = s; }
            int pos = atomicAdd(&indeg[d], 1);
            if (pos < ELLW) srcELL[d * ELLW + pos] = s;
        }
    }
}

// ---------- alpha1 via MFMA: [NN x 16] = x_bf[NN x 128] @ w1sT[16 x 128]^T ----------
__global__ __launch_bounds__(256) void alpha1_k(const bf16_t* __restrict__ x_bf,
                                                const bf16_t* __restrict__ w1sT,
                                                float* __restrict__ as1, float* __restrict__ ad1)
{
    const int wave = threadIdx.x >> 6, lane = threadIdx.x & 63;
    const int bm = blockIdx.x * 64 + wave * 16;
    const int lm = lane & 15, quad = lane >> 4;
    f32x4 acc = {};
    #pragma unroll
    for (int k0 = 0; k0 < F_IN; k0 += 32) {
        bf16x8 af = *(const bf16x8*)&x_bf[(size_t)(bm + lm) * F_IN + k0 + quad * 8];
        bf16x8 bf = *(const bf16x8*)&w1sT[lm * F_IN + k0 + quad * 8];
        acc = __builtin_amdgcn_mfma_f32_16x16x32_bf16(af, bf, acc, 0, 0, 0);
    }
    #pragma unroll
    for (int r = 0; r < 4; ++r) {
        int n = bm + quad * 4 + r;
        if (lm < 8) as1[n * HC1 + lm] = acc[r];
        else        ad1[n * HC1 + (lm - 8)] = acc[r];
    }
}

// ---------- layer-1 x-space aggregation: wave per node, all 8 heads ----------
__global__ __launch_bounds__(256) void aggx_k(const bf16_t* __restrict__ x_bf,
    const float* __restrict__ as1, const float* __restrict__ ad1,
    const int* __restrict__ indeg, const int* __restrict__ srcELL,
    bf16_t* __restrict__ xagg)
{
    const int wave = threadIdx.x >> 6, lane = threadIdx.x & 63;
    const int n = blockIdx.x * 4 + wave;
    const int c = lane * 2;
    const int deg = min(indeg[n], ELLW);

    int vsrc = 0;
    float vp[HC1] = {};
    if (lane < deg) {
        vsrc = srcELL[n * ELLW + lane];
        #pragma unroll
        for (int hd = 0; hd < HC1; ++hd) {
            float v = as1[vsrc * HC1 + hd] + ad1[n * HC1 + hd];
            v = (v > 0.f) ? v : NEG_SLOPE_F * v;
            vp[hd] = __expf(v);
        }
    }
    #pragma unroll
    for (int hd = 0; hd < HC1; ++hd) {
        float dsum = vp[hd];
        #pragma unroll
        for (int off = 1; off < 64; off <<= 1)
            dsum += __shfl_xor(dsum, off);
        vp[hd] *= 1.f / dsum;
    }

    float acc[HC1][2] = {};
    int ii = 0;
    for (; ii + 2 <= deg; ii += 2) {
        int s0 = __shfl(vsrc, ii), s1 = __shfl(vsrc, ii + 1);
        bf16x2 r0 = *(const bf16x2*)&x_bf[(size_t)s0 * F_IN + c];
        bf16x2 r1 = *(const bf16x2*)&x_bf[(size_t)s1 * F_IN + c];
        float f00 = (float)r0[0], f01 = (float)r0[1];
        float f10 = (float)r1[0], f11 = (float)r1[1];
        #pragma unroll
        for (int hd = 0; hd < HC1; ++hd) {
            float a0 = __shfl(vp[hd], ii);
            float a1 = __shfl(vp[hd], ii + 1);
            acc[hd][0] += a0 * f00 + a1 * f10;
            acc[hd][1] += a0 * f01 + a1 * f11;
        }
    }
    for (; ii < deg; ++ii) {
        int s = __shfl(vsrc, ii);
        bf16x2 rv = *(const bf16x2*)&x_bf[(size_t)s * F_IN + c];
        float r0 = (float)rv[0], r1 = (float)rv[1];
        #pragma unroll
        for (int hd = 0; hd < HC1; ++hd) {
            float al = __shfl(vp[hd], ii);
            acc[hd][0] += al * r0;
            acc[hd][1] += al * r1;
        }
    }
    #pragma unroll
    for (int hd = 0; hd < HC1; ++hd) {
        bf16x2 o;
        o[0] = (bf16_t)acc[hd][0];
        o[1] = (bf16_t)acc[hd][1];
        *(bf16x2*)&xagg[((size_t)n * HC1 + hd) * F_IN + c] = o;
    }
}

// ---------- per-head batched GEMM: out1[:, hd*512:+512] = relu(xagg[:,hd,:] @ W1h + b1) ----------
// double-buffered global_load_lds, 1 barrier per K-step.
// launch_bounds(256,3): 768 of 1024 blocks co-resident (makespan ~1.33 block-waves
// vs exactly 2 at (256,2)); VGPR cap ~170 avoids the (256,4) spill risk.
__global__ __launch_bounds__(256, 3) void gemmh_k(const bf16_t* __restrict__ xagg,
                                                  const bf16_t* __restrict__ Wt1,
                                                  const float* __restrict__ b1,
                                                  bf16_t* __restrict__ out1)
{
    __shared__ bf16_t As[2][128 * 32];
    __shared__ bf16_t Bs[2][128 * 32];
    const int tid = threadIdx.x;
    const int bm = blockIdx.x * 128, bn = blockIdx.y * 128;
    const int hd = blockIdx.z;

    const int wave = tid >> 6, lane = tid & 63;
    const int wm = wave >> 1, wn = wave & 1;
    const int lm = lane & 15, quad = lane >> 4;

    const int sr = tid >> 2;
    const int kg = tid & 3;
    const int swcol = (kg ^ (sr & 3)) * 8;   // inverse-swizzled source column group

    const bf16_t* Aptr = xagg + ((size_t)(bm + sr) * HC1 + hd) * F_IN + swcol;
    const bf16_t* Bptr = Wt1 + (size_t)(hd * CC + bn + sr) * F_IN + swcol;
    const size_t raskip = (size_t)64 * HC1 * F_IN;
    const size_t rbskip = (size_t)64 * F_IN;

    const int fswz = ((quad ^ (lm & 3)) * 8);

    f32x4 acc[4][4] = {};

    // prologue: stage k0=0 into buf 0
    gload_lds16(Aptr,          &As[0][tid * 8]);
    gload_lds16(Aptr + raskip, &As[0][2048 + tid * 8]);
    gload_lds16(Bptr,          &Bs[0][tid * 8]);
    gload_lds16(Bptr + rbskip, &Bs[0][2048 + tid * 8]);
    __syncthreads();                      // vmcnt(0): buf0 resident

    int cur = 0;
    for (int k0 = 0; k0 < F_IN; k0 += 32) {
        if (k0 + 32 < F_IN) {             // prefetch next tile into buf^1 (overlaps MFMA)
            const bf16_t* An = Aptr + (k0 + 32);
            const bf16_t* Bn = Bptr + (k0 + 32);
            gload_lds16(An,          &As[cur ^ 1][tid * 8]);
            gload_lds16(An + raskip, &As[cur ^ 1][2048 + tid * 8]);
            gload_lds16(Bn,          &Bs[cur ^ 1][tid * 8]);
            gload_lds16(Bn + rbskip, &Bs[cur ^ 1][2048 + tid * 8]);
        }
        const bf16_t* Ac = As[cur];
        const bf16_t* Bc = Bs[cur];
        bf16x8 af[4], bfr[4];
        #pragma unroll
        for (int i = 0; i < 4; ++i) {
            af[i]  = *(const bf16x8*)&Ac[(wm * 64 + i * 16 + lm) * 32 + fswz];
            bfr[i] = *(const bf16x8*)&Bc[(wn * 64 + i * 16 + lm) * 32 + fswz];
        }
        #pragma unroll
        for (int mt = 0; mt < 4; ++mt)
            #pragma unroll
            for (int nt = 0; nt < 4; ++nt)
                acc[mt][nt] = __builtin_amdgcn_mfma_f32_16x16x32_bf16(af[mt], bfr[nt], acc[mt][nt], 0, 0, 0);
        __syncthreads();                  // drains prefetch vmcnt + ds_read lgkmcnt
        cur ^= 1;
    }

    #pragma unroll
    for (int nt = 0; nt < 4; ++nt) {
        int gc = bn + wn * 64 + nt * 16 + lm;
        float bv = b1[hd * CC + gc];
        #pragma unroll
        for (int mt = 0; mt < 4; ++mt)
            #pragma unroll
            for (int r = 0; r < 4; ++r) {
                int gr = bm + wm * 64 + mt * 16 + quad * 4 + r;
                out1[(size_t)gr * 4096 + hd * CC + gc] = (bf16_t)fmaxf(acc[mt][nt][r] + bv, 0.f);
            }
    }
}

// ---------- 128x128 MFMA GEMM (NT), dbuf global_load_lds pipeline, split-K, bf16 partials ----------
__global__ __launch_bounds__(256, 2) void gemm128s_k(const bf16_t* __restrict__ A,
                                                     const bf16_t* __restrict__ Bt,
                                                     bf16_t* __restrict__ Cpart,
                                                     int M, int N, int K, int Kc)
{
    __shared__ bf16_t As[2][128 * 32];
    __shared__ bf16_t Bs[2][128 * 32];
    const int tid = threadIdx.x;
    const int bm = blockIdx.x * 128, bn = blockIdx.y * 128;
    const int kz = blockIdx.z;
    const int k_beg = kz * Kc;
    const int k_end = k_beg + Kc;

    const int wave = tid >> 6, lane = tid & 63;
    const int wm = wave >> 1, wn = wave & 1;
    const int lm = lane & 15, quad = lane >> 4;

    const int sr = tid >> 2;
    const int kg = tid & 3;
    const int swcol = (kg ^ (sr & 3)) * 8;   // inverse-swizzled source column group

    const bf16_t* Aptr = A + (size_t)(bm + sr) * K + k_beg + swcol;
    const bf16_t* Bptr = Bt + (size_t)(bn + sr) * K + k_beg + swcol;
    const size_t rowskip = (size_t)64 * K;

    const int fswz = ((quad ^ (lm & 3)) * 8);

    f32x4 acc[4][4] = {};

    // prologue: stage first K-step into buf 0
    gload_lds16(Aptr,           &As[0][tid * 8]);
    gload_lds16(Aptr + rowskip, &As[0][2048 + tid * 8]);
    gload_lds16(Bptr,           &Bs[0][tid * 8]);
    gload_lds16(Bptr + rowskip, &Bs[0][2048 + tid * 8]);
    __syncthreads();                      // vmcnt(0): buf0 resident

    int cur = 0;
    for (int k0 = k_beg; k0 < k_end; k0 += 32) {
        if (k0 + 32 < k_end) {            // prefetch next tile into buf^1 (overlaps MFMA)
            const bf16_t* An = Aptr + (k0 + 32 - k_beg);
            const bf16_t* Bn = Bptr + (k0 + 32 - k_beg);
            gload_lds16(An,           &As[cur ^ 1][tid * 8]);
            gload_lds16(An + rowskip, &As[cur ^ 1][2048 + tid * 8]);
            gload_lds16(Bn,           &Bs[cur ^ 1][tid * 8]);
            gload_lds16(Bn + rowskip, &Bs[cur ^ 1][2048 + tid * 8]);
        }
        const bf16_t* Ac = As[cur];
        const bf16_t* Bc = Bs[cur];
        bf16x8 af[4], bfr[4];
        #pragma unroll
        for (int i = 0; i < 4; ++i) {
            af[i]  = *(const bf16x8*)&Ac[(wm * 64 + i * 16 + lm) * 32 + fswz];
            bfr[i] = *(const bf16x8*)&Bc[(wn * 64 + i * 16 + lm) * 32 + fswz];
        }
        #pragma unroll
        for (int mt = 0; mt < 4; ++mt)
            #pragma unroll
            for (int nt = 0; nt < 4; ++nt)
                acc[mt][nt] = __builtin_amdgcn_mfma_f32_16x16x32_bf16(af[mt], bfr[nt], acc[mt][nt], 0, 0, 0);
        __syncthreads();                  // drains prefetch vmcnt + ds_read lgkmcnt
        cur ^= 1;
    }

    bf16_t* P = Cpart + (size_t)kz * M * N;
    #pragma unroll
    for (int nt = 0; nt < 4; ++nt) {
        int gc = bn + wn * 64 + nt * 16 + lm;
        #pragma unroll
        for (int mt = 0; mt < 4; ++mt)
            #pragma unroll
            for (int r = 0; r < 4; ++r) {
                int gr = bm + wm * 64 + mt * 16 + quad * 4 + r;
                P[(size_t)gr * N + gc] = (bf16_t)acc[mt][nt][r];
            }
    }
}

// ---------- layer-2 reduce: h2 = sum_{z<4} Pz (->bf16), fused as2/ad2 (atomic-free) ----------
// grid 2048, block 256: block covers rows 2b, 2b+1 (threads 0-127 row0, 128-255 row1)
__global__ __launch_bounds__(256) void reduce_h2_k(const bf16_t* __restrict__ P,
    const float* __restrict__ a_s, const float* __restrict__ a_d,
    bf16_t* __restrict__ h2bf, float* __restrict__ as2, float* __restrict__ ad2)
{
    __shared__ float sred[4][2];
    const int t = threadIdx.x;
    const int i = blockIdx.x * 1024 + t * 4;
    f32x4 s = {};
    #pragma unroll
    for (int z = 0; z < 4; ++z) {
        bf16x4 pv = *(const bf16x4*)&P[(size_t)z * NN * CC + i];
        #pragma unroll
        for (int j = 0; j < 4; ++j) s[j] += (float)pv[j];
    }
    bf16x4 o;
    #pragma unroll
    for (int j = 0; j < 4; ++j) o[j] = (bf16_t)s[j];
    *(bf16x4*)&h2bf[i] = o;

    const int c = (t & 127) * 4;
    f32x4 va = *(const f32x4*)&a_s[c];
    f32x4 vd = *(const f32x4*)&a_d[c];
    float ls = s[0]*va[0] + s[1]*va[1] + s[2]*va[2] + s[3]*va[3];
    float ld = s[0]*vd[0] + s[1]*vd[1] + s[2]*vd[2] + s[3]*vd[3];
    #pragma unroll
    for (int off = 32; off > 0; off >>= 1) {
        ls += __shfl_down(ls, off);
        ld += __shfl_down(ld, off);
    }
    const int wave = t >> 6, lane = t & 63;
    if (lane == 0) { sred[wave][0] = ls; sred[wave][1] = ld; }
    __syncthreads();
    if (t == 0) {
        as2[blockIdx.x * 2]     = sred[0][0] + sred[1][0];
        ad2[blockIdx.x * 2]     = sred[0][1] + sred[1][1];
    }
    if (t == 128) {
        as2[blockIdx.x * 2 + 1] = sred[2][0] + sred[3][0];
        ad2[blockIdx.x * 2 + 1] = sred[2][1] + sred[3][1];
    }
}

// ---------- fused tail: f1-row = relu(sum_16 bf16 partials + b); fc2; fc3 ----------
__global__ __launch_bounds__(128) void tail_k(const bf16_t* __restrict__ P,
                                              const float* __restrict__ fc1b,
                                              const float* __restrict__ fc2w,
                                              const float* __restrict__ fc2b,
                                              const float* __restrict__ fc3w,
                                              const float* __restrict__ fc3b,
                                              float* __restrict__ out)
{
    __shared__ float sA[512];
    __shared__ float sF2[128];
    const int m = blockIdx.x, t = threadIdx.x;
    const int MN = 512 * 512;
    #pragma unroll
    for (int i = 0; i < 4; ++i) {
        int c = t + i * 128;
        float v = 0.f;
        #pragma unroll
        for (int z = 0; z < 16; ++z)
            v += (float)P[(size_t)z * MN + (size_t)m * 512 + c];
        sA[c] = fmaxf(v + fc1b[c], 0.f);
    }
    __syncthreads();
    float a0 = 0.f, a1 = 0.f, a2 = 0.f, a3 = 0.f;
    #pragma unroll 4
    for (int k = 0; k < 512; k += 4) {
        a0 += sA[k + 0] * fc2w[(k + 0) * 128 + t];
        a1 += sA[k + 1] * fc2w[(k + 1) * 128 + t];
        a2 += sA[k + 2] * fc2w[(k + 2) * 128 + t];
        a3 += sA[k + 3] * fc2w[(k + 3) * 128 + t];
    }
    sF2[t] = fmaxf((a0 + a1) + (a2 + a3) + fc2b[t], 0.f);
    __syncthreads();
    if (t < 10) {
        float o = fc3b[t];
        #pragma unroll 4
        for (int k = 0; k < 128; ++k)
            o += sF2[k] * fc3w[k * 10 + t];
        out[(size_t)m * 10 + t] = o;
    }
}

// ---------- layer-2 aggregation: one WAVE per node, fused edge-softmax, ELL ----------
__global__ __launch_bounds__(256) void aggregate2_k(const bf16_t* __restrict__ hbuf,
    const float* __restrict__ as, const float* __restrict__ ad,
    const int* __restrict__ indeg, const int* __restrict__ srcELL,
    const float* __restrict__ bias, bf16_t* __restrict__ outb)
{
    const int g = blockIdx.x;
    const int wave = threadIdx.x >> 6, lane = threadIdx.x & 63;
    const int n = g * 4 + wave;
    const int c = lane * 8;

    const int deg = min(indeg[n], ELLW);
    const float adn = ad[n];

    int vsrc = 0; float vp = 0.f;
    if (lane < deg) {
        vsrc = srcELL[n * ELLW + lane];
        float v = as[vsrc] + adn;
        v = (v > 0.f) ? v : NEG_SLOPE_F * v;
        vp = __expf(v);
    }
    float denom = vp;
    #pragma unroll
    for (int off = 1; off < 64; off <<= 1)
        denom += __shfl_xor(denom, off);
    vp *= 1.f / denom;

    float acc[8] = {};
    int ii = 0;
    for (; ii + 4 <= deg; ii += 4) {
        int s0 = __shfl(vsrc, ii),     s1 = __shfl(vsrc, ii + 1);
        int s2 = __shfl(vsrc, ii + 2), s3 = __shfl(vsrc, ii + 3);
        float a0 = __shfl(vp, ii),     a1 = __shfl(vp, ii + 1);
        float a2 = __shfl(vp, ii + 2), a3 = __shfl(vp, ii + 3);
        bf16x8 r0 = *(const bf16x8*)&hbuf[(size_t)s0 * CC + c];
        bf16x8 r1 = *(const bf16x8*)&hbuf[(size_t)s1 * CC + c];
        bf16x8 r2 = *(const bf16x8*)&hbuf[(size_t)s2 * CC + c];
        bf16x8 r3 = *(const bf16x8*)&hbuf[(size_t)s3 * CC + c];
        #pragma unroll
        for (int j = 0; j < 8; ++j) {
            acc[j] += a0 * (float)r0[j];
            acc[j] += a1 * (float)r1[j];
            acc[j] += a2 * (float)r2[j];
            acc[j] += a3 * (float)r3[j];
        }
    }
    for (; ii < deg; ++ii) {
        int s = __shfl(vsrc, ii);
        float al = __shfl(vp, ii);
        bf16x8 rv = *(const bf16x8*)&hbuf[(size_t)s * CC + c];
        #pragma unroll
        for (int j = 0; j < 8; ++j)
            acc[j] += al * (float)rv[j];
    }
    size_t ob = (size_t)n * CC;
    bf16x8 o;
    #pragma unroll
    for (int j = 0; j < 8; ++j)
        o[j] = (bf16_t)fmaxf(acc[j] + bias[c + j], 0.f);
    *(bf16x8*)&outb[ob + c] = o;
}

extern "C" void kernel_launch(void* const* d_in, const int* in_sizes, int n_in,
                              void* d_out, int out_size, void* d_ws, size_t ws_size,
                              hipStream_t stream) {
    const float* x      = (const float*)d_in[0];
    const int*   ei     = (const int*)d_in[1];
    // d_in[2] edge_attr: ignored (GATConv has no edge_dim)
    const float* W1     = (const float*)d_in[3];
    const float* a_src1 = (const float*)d_in[4];
    const float* a_dst1 = (const float*)d_in[5];
    const float* b1     = (const float*)d_in[6];
    const float* W2     = (const float*)d_in[7];
    const float* a_src2 = (const float*)d_in[8];
    const float* a_dst2 = (const float*)d_in[9];
    const float* b2     = (const float*)d_in[10];
    const float* fc1w   = (const float*)d_in[11];
    const float* fc1b   = (const float*)d_in[12];
    const float* fc2w   = (const float*)d_in[13];
    const float* fc2b   = (const float*)d_in[14];
    const float* fc3w   = (const float*)d_in[15];
    const float* fc3b   = (const float*)d_in[16];
    float* out = (float*)d_out;

    // ---- workspace carve-up ----
    char* ws = (char*)d_ws;
    size_t o = 0;
    auto take = [&](size_t bytes) -> char* {
        char* p = ws + o;
        o = (o + bytes + 255) & ~(size_t)255;
        return p;
    };
    // zero-initialized block (indeg only)
    int*    indeg  = (int*)take(NN * 4);
    size_t zero_bytes = o;
    // rest
    float*  as2    = (float*)take(NN * 4);
    float*  ad2    = (float*)take(NN * 4);
    int*    srcELL = (int*)take((size_t)NN * ELLW * 4);
    float*  as1    = (float*)take((size_t)NN * HC1 * 4);
    float*  ad1    = (float*)take((size_t)NN * HC1 * 4);
    bf16_t* w1sT   = (bf16_t*)take((size_t)16 * F_IN * 2);
    bf16_t* x_bf   = (bf16_t*)take((size_t)NN * F_IN * 2);
    bf16_t* xagg   = (bf16_t*)take((size_t)NN * HC1 * F_IN * 2);   // [N][H][128]
    bf16_t* Wt1    = (bf16_t*)take((size_t)F_IN * 4096 * 2);       // [4096][128]
    bf16_t* Wt2    = (bf16_t*)take((size_t)4096 * 512 * 2);        // [512][4096]
    bf16_t* fc1wt  = (bf16_t*)take((size_t)4096 * 512 * 2);        // [512][4096]
    bf16_t* out1bf = (bf16_t*)take((size_t)NN * 4096 * 2);         // GAT1 out (bf16)
    bf16_t* h2bf   = (bf16_t*)take((size_t)NN * 512 * 2);          // GEMM2 out (bf16)
    bf16_t* out2bf = (bf16_t*)take((size_t)NN * 512 * 2);          // GAT2 out (bf16)
    bf16_t* part   = (bf16_t*)take((size_t)4 * NN * 512 * 2);      // split-K partials (bf16, 16 MB)

    hipMemsetAsync(d_ws, 0, zero_bytes, stream);

    // ---- fused prep (cast + 3 transposes + w1s + ELL edge build) ----
    prep_k<<<dim3(5296), dim3(256), 0, stream>>>(x, W1, W2, fc1w, a_src1, a_dst1, ei,
                                                 x_bf, Wt1, Wt2, fc1wt, w1sT,
                                                 srcELL, indeg);

    // ---- layer 1 (x-space aggregation; h1 never materialized) ----
    alpha1_k<<<dim3(64), dim3(256), 0, stream>>>(x_bf, w1sT, as1, ad1);
    aggx_k<<<dim3(NN / 4), dim3(256), 0, stream>>>(x_bf, as1, ad1, indeg, srcELL, xagg);
    gemmh_k<<<dim3(32, 4, 8), dim3(256), 0, stream>>>(xagg, Wt1, b1, out1bf);

    // ---- layer 2: h2 = out1 @ W2 (split-K=4, bf16 partials), fused alpha2 in reduce ----
    gemm128s_k<<<dim3(32, 4, 4), dim3(256), 0, stream>>>(
        out1bf, Wt2, part, 4096, 512, 4096, 1024);
    reduce_h2_k<<<dim3(NN / 2), dim3(256), 0, stream>>>(
        part, a_src2, a_dst2, h2bf, as2, ad2);
    aggregate2_k<<<dim3(NN / 4), dim3(256), 0, stream>>>(
        h2bf, as2, ad2, indeg, srcELL, b2, out2bf);

    // ---- MLP head: fc1 split-K=16 (bf16 partials), then fused reduce+fc2+fc3 ----
    gemm128s_k<<<dim3(4, 4, 16), dim3(256), 0, stream>>>(
        out2bf, fc1wt, part, 512, 512, 4096, 256);
    tail_k<<<dim3(512), dim3(128), 0, stream>>>(
        part, fc1b, fc2w, fc2b, fc3w, fc3b, out);
}

// Round 9
// 204.857 us; speedup vs baseline: 4.7047x; 1.0009x over previous
//
#include <hip/hip_runtime.h>
#include <cstdint>
#include <cstddef>

// Problem constants (fixed by the reference)
#define NN    4096      // nodes
#define E0C   32768     // raw edges
#define ETC   (E0C+NN)  // edges + self loops = 36864
#define HC1   8         // heads layer1
#define CC    512       // channels per head (both layers)
#define F_IN  128
#define NEG_SLOPE_F 0.2f
#define ELLW  64        // ELL width; max in-degree ~Poisson(9) << 64

typedef __bf16 bf16_t;
typedef __bf16 bf16x8 __attribute__((ext_vector_type(8)));
typedef __bf16 bf16x4 __attribute__((ext_vector_type(4)));
typedef __bf16 bf16x2 __attribute__((ext_vector_type(2)));
typedef float  f32x4  __attribute__((ext_vector_type(4)));

// async global->LDS, 16B per lane; LDS dest must be linear (wave-uniform base + lane*16)
__device__ __forceinline__ void gload_lds16(const void* g, void* l) {
    __builtin_amdgcn_global_load_lds(
        (const __attribute__((address_space(1))) void*)g,
        (__attribute__((address_space(3))) void*)l, 16, 0, 0);
}

// ---------- fused prep: region-dispatched ----------
// 32x32 f32->bf16 transpose tile, single-shot vectorized (G13):
//   read  float4 (16B/lane, 128B contiguous per 8-lane row group)
//   write bf16x4 (8B/lane, 64B contiguous per 8-lane row group)
// vs prior 4-iter scalar version: 4x fewer memory instructions.
// LDS [32][33]: both access phases are <=2-way bank-aliased (free, m136).
__device__ __forceinline__ void tcast_body(const float* __restrict__ W, bf16_t* __restrict__ Wt,
                                           int K, int N, int bx, int by)
{
    __shared__ float t[32][33];
    const int bn = bx * 32, bk = by * 32;
    const int r  = threadIdx.x >> 3;        // 0..31
    const int c0 = (threadIdx.x & 7) * 4;   // 0,4,...,28
    float4 v = *(const float4*)&W[(size_t)(bk + r) * N + bn + c0];
    t[r][c0 + 0] = v.x;
    t[r][c0 + 1] = v.y;
    t[r][c0 + 2] = v.z;
    t[r][c0 + 3] = v.w;
    __syncthreads();
    bf16x4 o;
    o[0] = (bf16_t)t[c0 + 0][r];
    o[1] = (bf16_t)t[c0 + 1][r];
    o[2] = (bf16_t)t[c0 + 2][r];
    o[3] = (bf16_t)t[c0 + 3][r];
    *(bf16x4*)&Wt[(size_t)(bn + r) * K + bk + c0] = o;
}

__global__ __launch_bounds__(256) void prep_k(const float* __restrict__ x,
    const float* __restrict__ W1, const float* __restrict__ W2,
    const float* __restrict__ fc1w, const float* __restrict__ a_src1,
    const float* __restrict__ a_dst1, const int* __restrict__ ei,
    bf16_t* __restrict__ x_bf, bf16_t* __restrict__ Wt1, bf16_t* __restrict__ Wt2,
    bf16_t* __restrict__ fc1wt, bf16_t* __restrict__ w1sT,
    int* __restrict__ srcELL, int* __restrict__ indeg)
{
    const int b = blockIdx.x;
    if (b < 512) {
        int i = (b * 256 + threadIdx.x) * 4;
        float4 v = *(const float4*)&x[i];
        bf16x4 o;
        o[0] = (bf16_t)v.x; o[1] = (bf16_t)v.y; o[2] = (bf16_t)v.z; o[3] = (bf16_t)v.w;
        *(bf16x4*)&x_bf[i] = o;
    } else if (b < 1024) {
        int bl = b - 512;
        tcast_body(W1, Wt1, F_IN, 4096, bl % 128, bl / 128);
    } else if (b < 3072) {
        int bl = b - 1024;
        tcast_body(W2, Wt2, 4096, 512, bl % 16, bl / 16);
    } else if (b < 5120) {
        int bl = b - 3072;
        tcast_body(fc1w, fc1wt, 4096, 512, bl % 16, bl / 16);
    } else if (b < 5152) {
        int bl = b - 5120;                     // 0..31
        int wave = threadIdx.x >> 6, lane = threadIdx.x & 63;
        int k = bl * 4 + wave;                 // 0..127
        int hd = lane >> 3;
        int co = (lane & 7) * 64;
        const float* wrow = W1 + (size_t)k * (HC1 * CC) + hd * CC + co;
        const float* vs = a_src1 + hd * CC + co;
        const float* vd = a_dst1 + hd * CC + co;
        float s = 0.f, d = 0.f;
        #pragma unroll 4
        for (int t = 0; t < 64; ++t) {
            float w = wrow[t];
            s += w * vs[t];
            d += w * vd[t];
        }
        #pragma unroll
        for (int off = 1; off < 8; off <<= 1) {
            s += __shfl_xor(s, off);
            d += __shfl_xor(d, off);
        }
        if ((lane & 7) == 0) {
            w1sT[hd * F_IN + k]       = (bf16_t)s;
            w1sT[(hd + 8) * F_IN + k] = (bf16_t)d;
        }
    } else {
        int e = (b - 5152) * 256 + threadIdx.x;
        if (e < ETC) {
            int s, d;
            if (e < E0C) { s = ei[e]; d = ei[E0C + e]; }
            else         { s = e - E0C; d = s; }
            int pos = atomicAdd(&indeg[d], 1);
            if (pos < ELLW) srcELL[d * ELLW + pos] = s;
        }
    }
}

// ---------- alpha1 via MFMA: [NN x 16] = x_bf[NN x 128] @ w1sT[16 x 128]^T ----------
__global__ __launch_bounds__(256) void alpha1_k(const bf16_t* __restrict__ x_bf,
                                                const bf16_t* __restrict__ w1sT,
                                                float* __restrict__ as1, float* __restrict__ ad1)
{
    const int wave = threadIdx.x >> 6, lane = threadIdx.x & 63;
    const int bm = blockIdx.x * 64 + wave * 16;
    const int lm = lane & 15, quad = lane >> 4;
    f32x4 acc = {};
    #pragma unroll
    for (int k0 = 0; k0 < F_IN; k0 += 32) {
        bf16x8 af = *(const bf16x8*)&x_bf[(size_t)(bm + lm) * F_IN + k0 + quad * 8];
        bf16x8 bf = *(const bf16x8*)&w1sT[lm * F_IN + k0 + quad * 8];
        acc = __builtin_amdgcn_mfma_f32_16x16x32_bf16(af, bf, acc, 0, 0, 0);
    }
    #pragma unroll
    for (int r = 0; r < 4; ++r) {
        int n = bm + quad * 4 + r;
        if (lm < 8) as1[n * HC1 + lm] = acc[r];
        else        ad1[n * HC1 + (lm - 8)] = acc[r];
    }
}

// ---------- layer-1 x-space aggregation: wave per node, all 8 heads ----------
__global__ __launch_bounds__(256) void aggx_k(const bf16_t* __restrict__ x_bf,
    const float* __restrict__ as1, const float* __restrict__ ad1,
    const int* __restrict__ indeg, const int* __restrict__ srcELL,
    bf16_t* __restrict__ xagg)
{
    const int wave = threadIdx.x >> 6, lane = threadIdx.x & 63;
    const int n = blockIdx.x * 4 + wave;
    const int c = lane * 2;
    const int deg = min(indeg[n], ELLW);

    int vsrc = 0;
    float vp[HC1] = {};
    if (lane < deg) {
        vsrc = srcELL[n * ELLW + lane];
        #pragma unroll
        for (int hd = 0; hd < HC1; ++hd) {
            float v = as1[vsrc * HC1 + hd] + ad1[n * HC1 + hd];
            v = (v > 0.f) ? v : NEG_SLOPE_F * v;
            vp[hd] = __expf(v);
        }
    }
    #pragma unroll
    for (int hd = 0; hd < HC1; ++hd) {
        float dsum = vp[hd];
        #pragma unroll
        for (int off = 1; off < 64; off <<= 1)
            dsum += __shfl_xor(dsum, off);
        vp[hd] *= 1.f / dsum;
    }

    float acc[HC1][2] = {};
    int ii = 0;
    for (; ii + 2 <= deg; ii += 2) {
        int s0 = __shfl(vsrc, ii), s1 = __shfl(vsrc, ii + 1);
        bf16x2 r0 = *(const bf16x2*)&x_bf[(size_t)s0 * F_IN + c];
        bf16x2 r1 = *(const bf16x2*)&x_bf[(size_t)s1 * F_IN + c];
        float f00 = (float)r0[0], f01 = (float)r0[1];
        float f10 = (float)r1[0], f11 = (float)r1[1];
        #pragma unroll
        for (int hd = 0; hd < HC1; ++hd) {
            float a0 = __shfl(vp[hd], ii);
            float a1 = __shfl(vp[hd], ii + 1);
            acc[hd][0] += a0 * f00 + a1 * f10;
            acc[hd][1] += a0 * f01 + a1 * f11;
        }
    }
    for (; ii < deg; ++ii) {
        int s = __shfl(vsrc, ii);
        bf16x2 rv = *(const bf16x2*)&x_bf[(size_t)s * F_IN + c];
        float r0 = (float)rv[0], r1 = (float)rv[1];
        #pragma unroll
        for (int hd = 0; hd < HC1; ++hd) {
            float al = __shfl(vp[hd], ii);
            acc[hd][0] += al * r0;
            acc[hd][1] += al * r1;
        }
    }
    #pragma unroll
    for (int hd = 0; hd < HC1; ++hd) {
        bf16x2 o;
        o[0] = (bf16_t)acc[hd][0];
        o[1] = (bf16_t)acc[hd][1];
        *(bf16x2*)&xagg[((size_t)n * HC1 + hd) * F_IN + c] = o;
    }
}

// ---------- per-head batched GEMM: out1[:, hd*512:+512] = relu(xagg[:,hd,:] @ W1h + b1) ----------
// double-buffered global_load_lds, 1 barrier per K-step; launch_bounds(256,3)
__global__ __launch_bounds__(256, 3) void gemmh_k(const bf16_t* __restrict__ xagg,
                                                  const bf16_t* __restrict__ Wt1,
                                                  const float* __restrict__ b1,
                                                  bf16_t* __restrict__ out1)
{
    __shared__ bf16_t As[2][128 * 32];
    __shared__ bf16_t Bs[2][128 * 32];
    const int tid = threadIdx.x;
    const int bm = blockIdx.x * 128, bn = blockIdx.y * 128;
    const int hd = blockIdx.z;

    const int wave = tid >> 6, lane = tid & 63;
    const int wm = wave >> 1, wn = wave & 1;
    const int lm = lane & 15, quad = lane >> 4;

    const int sr = tid >> 2;
    const int kg = tid & 3;
    const int swcol = (kg ^ (sr & 3)) * 8;   // inverse-swizzled source column group

    const bf16_t* Aptr = xagg + ((size_t)(bm + sr) * HC1 + hd) * F_IN + swcol;
    const bf16_t* Bptr = Wt1 + (size_t)(hd * CC + bn + sr) * F_IN + swcol;
    const size_t raskip = (size_t)64 * HC1 * F_IN;
    const size_t rbskip = (size_t)64 * F_IN;

    const int fswz = ((quad ^ (lm & 3)) * 8);

    f32x4 acc[4][4] = {};

    // prologue: stage k0=0 into buf 0
    gload_lds16(Aptr,          &As[0][tid * 8]);
    gload_lds16(Aptr + raskip, &As[0][2048 + tid * 8]);
    gload_lds16(Bptr,          &Bs[0][tid * 8]);
    gload_lds16(Bptr + rbskip, &Bs[0][2048 + tid * 8]);
    __syncthreads();                      // vmcnt(0): buf0 resident

    int cur = 0;
    for (int k0 = 0; k0 < F_IN; k0 += 32) {
        if (k0 + 32 < F_IN) {             // prefetch next tile into buf^1 (overlaps MFMA)
            const bf16_t* An = Aptr + (k0 + 32);
            const bf16_t* Bn = Bptr + (k0 + 32);
            gload_lds16(An,          &As[cur ^ 1][tid * 8]);
            gload_lds16(An + raskip, &As[cur ^ 1][2048 + tid * 8]);
            gload_lds16(Bn,          &Bs[cur ^ 1][tid * 8]);
            gload_lds16(Bn + rbskip, &Bs[cur ^ 1][2048 + tid * 8]);
        }
        const bf16_t* Ac = As[cur];
        const bf16_t* Bc = Bs[cur];
        bf16x8 af[4], bfr[4];
        #pragma unroll
        for (int i = 0; i < 4; ++i) {
            af[i]  = *(const bf16x8*)&Ac[(wm * 64 + i * 16 + lm) * 32 + fswz];
            bfr[i] = *(const bf16x8*)&Bc[(wn * 64 + i * 16 + lm) * 32 + fswz];
        }
        #pragma unroll
        for (int mt = 0; mt < 4; ++mt)
            #pragma unroll
            for (int nt = 0; nt < 4; ++nt)
                acc[mt][nt] = __builtin_amdgcn_mfma_f32_16x16x32_bf16(af[mt], bfr[nt], acc[mt][nt], 0, 0, 0);
        __syncthreads();                  // drains prefetch vmcnt + ds_read lgkmcnt
        cur ^= 1;
    }

    #pragma unroll
    for (int nt = 0; nt < 4; ++nt) {
        int gc = bn + wn * 64 + nt * 16 + lm;
        float bv = b1[hd * CC + gc];
        #pragma unroll
        for (int mt = 0; mt < 4; ++mt)
            #pragma unroll
            for (int r = 0; r < 4; ++r) {
                int gr = bm + wm * 64 + mt * 16 + quad * 4 + r;
                out1[(size_t)gr * 4096 + hd * CC + gc] = (bf16_t)fmaxf(acc[mt][nt][r] + bv, 0.f);
            }
    }
}

// ---------- 128x128 MFMA GEMM (NT), dbuf global_load_lds pipeline, split-K, bf16 partials ----------
__global__ __launch_bounds__(256, 2) void gemm128s_k(const bf16_t* __restrict__ A,
                                                     const bf16_t* __restrict__ Bt,
                                                     bf16_t* __restrict__ Cpart,
                                                     int M, int N, int K, int Kc)
{
    __shared__ bf16_t As[2][128 * 32];
    __shared__ bf16_t Bs[2][128 * 32];
    const int tid = threadIdx.x;
    const int bm = blockIdx.x * 128, bn = blockIdx.y * 128;
    const int kz = blockIdx.z;
    const int k_beg = kz * Kc;
    const int k_end = k_beg + Kc;

    const int wave = tid >> 6, lane = tid & 63;
    const int wm = wave >> 1, wn = wave & 1;
    const int lm = lane & 15, quad = lane >> 4;

    const int sr = tid >> 2;
    const int kg = tid & 3;
    const int swcol = (kg ^ (sr & 3)) * 8;   // inverse-swizzled source column group

    const bf16_t* Aptr = A + (size_t)(bm + sr) * K + k_beg + swcol;
    const bf16_t* Bptr = Bt + (size_t)(bn + sr) * K + k_beg + swcol;
    const size_t rowskip = (size_t)64 * K;

    const int fswz = ((quad ^ (lm & 3)) * 8);

    f32x4 acc[4][4] = {};

    // prologue: stage first K-step into buf 0
    gload_lds16(Aptr,           &As[0][tid * 8]);
    gload_lds16(Aptr + rowskip, &As[0][2048 + tid * 8]);
    gload_lds16(Bptr,           &Bs[0][tid * 8]);
    gload_lds16(Bptr + rowskip, &Bs[0][2048 + tid * 8]);
    __syncthreads();                      // vmcnt(0): buf0 resident

    int cur = 0;
    for (int k0 = k_beg; k0 < k_end; k0 += 32) {
        if (k0 + 32 < k_end) {            // prefetch next tile into buf^1 (overlaps MFMA)
            const bf16_t* An = Aptr + (k0 + 32 - k_beg);
            const bf16_t* Bn = Bptr + (k0 + 32 - k_beg);
            gload_lds16(An,           &As[cur ^ 1][tid * 8]);
            gload_lds16(An + rowskip, &As[cur ^ 1][2048 + tid * 8]);
            gload_lds16(Bn,           &Bs[cur ^ 1][tid * 8]);
            gload_lds16(Bn + rowskip, &Bs[cur ^ 1][2048 + tid * 8]);
        }
        const bf16_t* Ac = As[cur];
        const bf16_t* Bc = Bs[cur];
        bf16x8 af[4], bfr[4];
        #pragma unroll
        for (int i = 0; i < 4; ++i) {
            af[i]  = *(const bf16x8*)&Ac[(wm * 64 + i * 16 + lm) * 32 + fswz];
            bfr[i] = *(const bf16x8*)&Bc[(wn * 64 + i * 16 + lm) * 32 + fswz];
        }
        #pragma unroll
        for (int mt = 0; mt < 4; ++mt)
            #pragma unroll
            for (int nt = 0; nt < 4; ++nt)
                acc[mt][nt] = __builtin_amdgcn_mfma_f32_16x16x32_bf16(af[mt], bfr[nt], acc[mt][nt], 0, 0, 0);
        __syncthreads();                  // drains prefetch vmcnt + ds_read lgkmcnt
        cur ^= 1;
    }

    bf16_t* P = Cpart + (size_t)kz * M * N;
    #pragma unroll
    for (int nt = 0; nt < 4; ++nt) {
        int gc = bn + wn * 64 + nt * 16 + lm;
        #pragma unroll
        for (int mt = 0; mt < 4; ++mt)
            #pragma unroll
            for (int r = 0; r < 4; ++r) {
                int gr = bm + wm * 64 + mt * 16 + quad * 4 + r;
                P[(size_t)gr * N + gc] = (bf16_t)acc[mt][nt][r];
            }
    }
}

// ---------- layer-2 reduce: h2 = sum_{z<4} Pz (->bf16), fused as2/ad2 (atomic-free) ----------
// grid 2048, block 256: block covers rows 2b, 2b+1 (threads 0-127 row0, 128-255 row1)
__global__ __launch_bounds__(256) void reduce_h2_k(const bf16_t* __restrict__ P,
    const float* __restrict__ a_s, const float* __restrict__ a_d,
    bf16_t* __restrict__ h2bf, float* __restrict__ as2, float* __restrict__ ad2)
{
    __shared__ float sred[4][2];
    const int t = threadIdx.x;
    const int i = blockIdx.x * 1024 + t * 4;
    f32x4 s = {};
    #pragma unroll
    for (int z = 0; z < 4; ++z) {
        bf16x4 pv = *(const bf16x4*)&P[(size_t)z * NN * CC + i];
        #pragma unroll
        for (int j = 0; j < 4; ++j) s[j] += (float)pv[j];
    }
    bf16x4 o;
    #pragma unroll
    for (int j = 0; j < 4; ++j) o[j] = (bf16_t)s[j];
    *(bf16x4*)&h2bf[i] = o;

    const int c = (t & 127) * 4;
    f32x4 va = *(const f32x4*)&a_s[c];
    f32x4 vd = *(const f32x4*)&a_d[c];
    float ls = s[0]*va[0] + s[1]*va[1] + s[2]*va[2] + s[3]*va[3];
    float ld = s[0]*vd[0] + s[1]*vd[1] + s[2]*vd[2] + s[3]*vd[3];
    #pragma unroll
    for (int off = 32; off > 0; off >>= 1) {
        ls += __shfl_down(ls, off);
        ld += __shfl_down(ld, off);
    }
    const int wave = t >> 6, lane = t & 63;
    if (lane == 0) { sred[wave][0] = ls; sred[wave][1] = ld; }
    __syncthreads();
    if (t == 0) {
        as2[blockIdx.x * 2]     = sred[0][0] + sred[1][0];
        ad2[blockIdx.x * 2]     = sred[0][1] + sred[1][1];
    }
    if (t == 128) {
        as2[blockIdx.x * 2 + 1] = sred[2][0] + sred[3][0];
        ad2[blockIdx.x * 2 + 1] = sred[2][1] + sred[3][1];
    }
}

// ---------- fused tail: f1-row = relu(sum_16 bf16 partials + b); fc2; fc3 ----------
__global__ __launch_bounds__(128) void tail_k(const bf16_t* __restrict__ P,
                                              const float* __restrict__ fc1b,
                                              const float* __restrict__ fc2w,
                                              const float* __restrict__ fc2b,
                                              const float* __restrict__ fc3w,
                                              const float* __restrict__ fc3b,
                                              float* __restrict__ out)
{
    __shared__ float sA[512];
    __shared__ float sF2[128];
    const int m = blockIdx.x, t = threadIdx.x;
    const int MN = 512 * 512;
    #pragma unroll
    for (int i = 0; i < 4; ++i) {
        int c = t + i * 128;
        float v = 0.f;
        #pragma unroll
        for (int z = 0; z < 16; ++z)
            v += (float)P[(size_t)z * MN + (size_t)m * 512 + c];
        sA[c] = fmaxf(v + fc1b[c], 0.f);
    }
    __syncthreads();
    float a0 = 0.f, a1 = 0.f, a2 = 0.f, a3 = 0.f;
    #pragma unroll 4
    for (int k = 0; k < 512; k += 4) {
        a0 += sA[k + 0] * fc2w[(k + 0) * 128 + t];
        a1 += sA[k + 1] * fc2w[(k + 1) * 128 + t];
        a2 += sA[k + 2] * fc2w[(k + 2) * 128 + t];
        a3 += sA[k + 3] * fc2w[(k + 3) * 128 + t];
    }
    sF2[t] = fmaxf((a0 + a1) + (a2 + a3) + fc2b[t], 0.f);
    __syncthreads();
    if (t < 10) {
        float o = fc3b[t];
        #pragma unroll 4
        for (int k = 0; k < 128; ++k)
            o += sF2[k] * fc3w[k * 10 + t];
        out[(size_t)m * 10 + t] = o;
    }
}

// ---------- layer-2 aggregation: one WAVE per node, fused edge-softmax, ELL ----------
__global__ __launch_bounds__(256) void aggregate2_k(const bf16_t* __restrict__ hbuf,
    const float* __restrict__ as, const float* __restrict__ ad,
    const int* __restrict__ indeg, const int* __restrict__ srcELL,
    const float* __restrict__ bias, bf16_t* __restrict__ outb)
{
    const int g = blockIdx.x;
    const int wave = threadIdx.x >> 6, lane = threadIdx.x & 63;
    const int n = g * 4 + wave;
    const int c = lane * 8;

    const int deg = min(indeg[n], ELLW);
    const float adn = ad[n];

    int vsrc = 0; float vp = 0.f;
    if (lane < deg) {
        vsrc = srcELL[n * ELLW + lane];
        float v = as[vsrc] + adn;
        v = (v > 0.f) ? v : NEG_SLOPE_F * v;
        vp = __expf(v);
    }
    float denom = vp;
    #pragma unroll
    for (int off = 1; off < 64; off <<= 1)
        denom += __shfl_xor(denom, off);
    vp *= 1.f / denom;

    float acc[8] = {};
    int ii = 0;
    for (; ii + 4 <= deg; ii += 4) {
        int s0 = __shfl(vsrc, ii),     s1 = __shfl(vsrc, ii + 1);
        int s2 = __shfl(vsrc, ii + 2), s3 = __shfl(vsrc, ii + 3);
        float a0 = __shfl(vp, ii),     a1 = __shfl(vp, ii + 1);
        float a2 = __shfl(vp, ii + 2), a3 = __shfl(vp, ii + 3);
        bf16x8 r0 = *(const bf16x8*)&hbuf[(size_t)s0 * CC + c];
        bf16x8 r1 = *(const bf16x8*)&hbuf[(size_t)s1 * CC + c];
        bf16x8 r2 = *(const bf16x8*)&hbuf[(size_t)s2 * CC + c];
        bf16x8 r3 = *(const bf16x8*)&hbuf[(size_t)s3 * CC + c];
        #pragma unroll
        for (int j = 0; j < 8; ++j) {
            acc[j] += a0 * (float)r0[j];
            acc[j] += a1 * (float)r1[j];
            acc[j] += a2 * (float)r2[j];
            acc[j] += a3 * (float)r3[j];
        }
    }
    for (; ii < deg; ++ii) {
        int s = __shfl(vsrc, ii);
        float al = __shfl(vp, ii);
        bf16x8 rv = *(const bf16x8*)&hbuf[(size_t)s * CC + c];
        #pragma unroll
        for (int j = 0; j < 8; ++j)
            acc[j] += al * (float)rv[j];
    }
    size_t ob = (size_t)n * CC;
    bf16x8 o;
    #pragma unroll
    for (int j = 0; j < 8; ++j)
        o[j] = (bf16_t)fmaxf(acc[j] + bias[c + j], 0.f);
    *(bf16x8*)&outb[ob + c] = o;
}

extern "C" void kernel_launch(void* const* d_in, const int* in_sizes, int n_in,
                              void* d_out, int out_size, void* d_ws, size_t ws_size,
                              hipStream_t stream) {
    const float* x      = (const float*)d_in[0];
    const int*   ei     = (const int*)d_in[1];
    // d_in[2] edge_attr: ignored (GATConv has no edge_dim)
    const float* W1     = (const float*)d_in[3];
    const float* a_src1 = (const float*)d_in[4];
    const float* a_dst1 = (const float*)d_in[5];
    const float* b1     = (const float*)d_in[6];
    const float* W2     = (const float*)d_in[7];
    const float* a_src2 = (const float*)d_in[8];
    const float* a_dst2 = (const float*)d_in[9];
    const float* b2     = (const float*)d_in[10];
    const float* fc1w   = (const float*)d_in[11];
    const float* fc1b   = (const float*)d_in[12];
    const float* fc2w   = (const float*)d_in[13];
    const float* fc2b   = (const float*)d_in[14];
    const float* fc3w   = (const float*)d_in[15];
    const float* fc3b   = (const float*)d_in[16];
    float* out = (float*)d_out;

    // ---- workspace carve-up ----
    char* ws = (char*)d_ws;
    size_t o = 0;
    auto take = [&](size_t bytes) -> char* {
        char* p = ws + o;
        o = (o + bytes + 255) & ~(size_t)255;
        return p;
    };
    // zero-initialized block (indeg only)
    int*    indeg  = (int*)take(NN * 4);
    size_t zero_bytes = o;
    // rest
    float*  as2    = (float*)take(NN * 4);
    float*  ad2    = (float*)take(NN * 4);
    int*    srcELL = (int*)take((size_t)NN * ELLW * 4);
    float*  as1    = (float*)take((size_t)NN * HC1 * 4);
    float*  ad1    = (float*)take((size_t)NN * HC1 * 4);
    bf16_t* w1sT   = (bf16_t*)take((size_t)16 * F_IN * 2);
    bf16_t* x_bf   = (bf16_t*)take((size_t)NN * F_IN * 2);
    bf16_t* xagg   = (bf16_t*)take((size_t)NN * HC1 * F_IN * 2);   // [N][H][128]
    bf16_t* Wt1    = (bf16_t*)take((size_t)F_IN * 4096 * 2);       // [4096][128]
    bf16_t* Wt2    = (bf16_t*)take((size_t)4096 * 512 * 2);        // [512][4096]
    bf16_t* fc1wt  = (bf16_t*)take((size_t)4096 * 512 * 2);        // [512][4096]
    bf16_t* out1bf = (bf16_t*)take((size_t)NN * 4096 * 2);         // GAT1 out (bf16)
    bf16_t* h2bf   = (bf16_t*)take((size_t)NN * 512 * 2);          // GEMM2 out (bf16)
    bf16_t* out2bf = (bf16_t*)take((size_t)NN * 512 * 2);          // GAT2 out (bf16)
    bf16_t* part   = (bf16_t*)take((size_t)4 * NN * 512 * 2);      // split-K partials (bf16, 16 MB)

    hipMemsetAsync(d_ws, 0, zero_bytes, stream);

    // ---- fused prep (cast + 3 transposes + w1s + ELL edge build) ----
    prep_k<<<dim3(5296), dim3(256), 0, stream>>>(x, W1, W2, fc1w, a_src1, a_dst1, ei,
                                                 x_bf, Wt1, Wt2, fc1wt, w1sT,
                                                 srcELL, indeg);

    // ---- layer 1 (x-space aggregation; h1 never materialized) ----
    alpha1_k<<<dim3(64), dim3(256), 0, stream>>>(x_bf, w1sT, as1, ad1);
    aggx_k<<<dim3(NN / 4), dim3(256), 0, stream>>>(x_bf, as1, ad1, indeg, srcELL, xagg);
    gemmh_k<<<dim3(32, 4, 8), dim3(256), 0, stream>>>(xagg, Wt1, b1, out1bf);

    // ---- layer 2: h2 = out1 @ W2 (split-K=4, bf16 partials), fused alpha2 in reduce ----
    gemm128s_k<<<dim3(32, 4, 4), dim3(256), 0, stream>>>(
        out1bf, Wt2, part, 4096, 512, 4096, 1024);
    reduce_h2_k<<<dim3(NN / 2), dim3(256), 0, stream>>>(
        part, a_src2, a_dst2, h2bf, as2, ad2);
    aggregate2_k<<<dim3(NN / 4), dim3(256), 0, stream>>>(
        h2bf, as2, ad2, indeg, srcELL, b2, out2bf);

    // ---- MLP head: fc1 split-K=16 (bf16 partials), then fused reduce+fc2+fc3 ----
    gemm128s_k<<<dim3(4, 4, 16), dim3(256), 0, stream>>>(
        out2bf, fc1wt, part, 512, 512, 4096, 256);
    tail_k<<<dim3(512), dim3(128), 0, stream>>>(
        part, fc1b, fc2w, fc2b, fc3w, fc3b, out);
}